// Round 1
// baseline (351.794 us; speedup 1.0000x reference)
//
#include <hip/hip_runtime.h>
#include <hip/hip_bf16.h>

typedef unsigned int u32;
typedef unsigned short u16;
typedef __attribute__((ext_vector_type(8))) short short8;   // 8 bf16 (4 VGPRs) MFMA A/B frag
typedef __attribute__((ext_vector_type(4))) float f32x4;    // MFMA C/D frag
typedef __attribute__((ext_vector_type(4))) u32 u32x4;
typedef __attribute__((ext_vector_type(2))) u32 u32x2;

#define DD 32
#define EE 8
#define HH 64
#define TT 10
#define BATCH 16384
#define EPB 32          // batch elements per block; grid 512 = 2 blocks/CU
#define DYN_LDS 62464   // bytes: xdb 2560 + fsb 16896 + lg 1536 + usb 4608 + hs 36864

#if __has_builtin(__builtin_amdgcn_exp2f)
#define EXP2F(x) __builtin_amdgcn_exp2f(x)
#else
#define EXP2F(x) __builtin_exp2f(x)
#endif

__device__ __forceinline__ float fast_tanh(float x) {
  float e = EXP2F(x * 2.885390082f);
  return 1.f - 2.f * __builtin_amdgcn_rcpf(e + 1.f);
}
__device__ __forceinline__ u16 f2b_rn(float v) {
  return (u16)((__float_as_uint(v) + 0x8000u) >> 16);
}
__device__ __forceinline__ u32 pack2_rn(float a, float b) {
  return __builtin_amdgcn_perm(__float_as_uint(b) + 0x8000u,
                               __float_as_uint(a) + 0x8000u, 0x07060302u);
}
__device__ __forceinline__ float unp_lo(u32 p) { return __uint_as_float(p << 16); }
__device__ __forceinline__ float unp_hi(u32 p) { return __uint_as_float(p & 0xffff0000u); }
__device__ __forceinline__ short8 lds_frag(const u32* p) {
  u32x4 v = *(const u32x4*)p;               // ds_read_b128 (16B-aligned by construction)
  return __builtin_bit_cast(short8, v);
}
__device__ __forceinline__ f32x4 bcast4(float v) { f32x4 c; c[0]=v; c[1]=v; c[2]=v; c[3]=v; return c; }

// wave = expert (8 waves, 512 thr). R14: EPB 64 -> 32, grid 256 -> 512.
// Rationale: R12's 88 KB LDS forced 1 block/CU (8 waves); the 4 barriers/stage
// dependency chain (f -> U -> logits -> C) then has nothing to overlap with,
// capping VALU ~63% / DS ~64%. 62.4 KB LDS fits 2 blocks/CU -> two INDEPENDENT
// barrier groups per CU (16 waves, HW law waves/CU ~ floor(2048/VGPR), m69) so
// one block's compute fills the other's barrier stalls. Measured-optimal LDS
// layouts from R12 kept verbatim (plain stride-132 fsb rows — R13's swizzle
// regressed; per-wave ping-pong h-scratch). VGPR must stay <= 128: this version
// REMOVES ~12 VGPRs vs R12 (bg1x/bg1f 2->1 frags, xst/xacc 4->2) — plain
// __launch_bounds__(512) only, no cap (caps <=128 spill the weight frags).
__global__ __launch_bounds__(512) void ame_ode_kernel(
    const float* __restrict__ x0, const float* __restrict__ tspan,
    const float* __restrict__ W1, const float* __restrict__ b1,
    const float* __restrict__ W2, const float* __restrict__ b2,
    const float* __restrict__ W3, const float* __restrict__ b3,
    const float* __restrict__ Gw1, const float* __restrict__ Gb1,
    const float* __restrict__ Gw2, const float* __restrict__ Gb2,
    float* __restrict__ out)
{
  extern __shared__ __align__(16) u32 dynbuf[];
  u32*  const xdb = dynbuf;                    // [EPB][20] u32: xs bf16x2 (2560 B)
  u32*  const fsb = dynbuf + 640;              // [EPB][132] u32: f bf16x2, 16B-aligned rows (16896 B)
  float* const lg = (float*)(dynbuf + 4864);   // [EPB][12]: logits (1536 B)
  u32*  const usb = dynbuf + 5248;             // [EPB][36] u32: gating U (4608 B)
  u32*  const hs  = dynbuf + 6400;             // [8 waves][2 regions][16][36] u32 scratch (36864 B)

  const int tid  = threadIdx.x;
  const int lane = tid & 63;
  const int l15  = lane & 15;
  const int quad = lane >> 4;
  const int e    = __builtin_amdgcn_readfirstlane(tid >> 6);   // wave-uniform expert id

  // phase-C mapping: 16 threads per elem, 2 dims each
  const int cm = tid & 31;                     // batch elem (block-local)
  const int cg = tid >> 5;                     // dim-pair index 0..15 (dims 2cg, 2cg+1)
  const int cb = blockIdx.x * EPB + cm;        // global batch element

  const float* W1f = W1 + e * (DD + 1) * HH;
  const float* b1f = b1 + e * HH;
  const float* W2f = W2 + e * HH * HH;
  const float* b2f = b2 + e * HH;
  const float* W3f = W3 + e * HH * DD;
  const float* b3f = b3 + e * DD;

  // ---- expert-weight B-frags: B[k=quad*8+j][n=l15(+16nt)] ----
  short8 bw1[4], bw2[2][4], bw3[2][2];
  #pragma unroll
  for (int nt = 0; nt < 4; nt++)
    #pragma unroll
    for (int j = 0; j < 8; j++)
      bw1[nt][j] = (short)f2b_rn(W1f[(quad * 8 + j) * HH + nt * 16 + l15]);
  #pragma unroll
  for (int ks = 0; ks < 2; ks++)
    #pragma unroll
    for (int nt = 0; nt < 4; nt++)
      #pragma unroll
      for (int j = 0; j < 8; j++)
        bw2[ks][nt][j] = (short)f2b_rn(W2f[(ks * 32 + quad * 8 + j) * HH + nt * 16 + l15]);
  #pragma unroll
  for (int ks = 0; ks < 2; ks++)
    #pragma unroll
    for (int dt2 = 0; dt2 < 2; dt2++)
      #pragma unroll
      for (int j = 0; j < 8; j++)
        bw3[ks][dt2][j] = (short)f2b_rn(W3f[(ks * 32 + quad * 8 + j) * DD + dt2 * 16 + l15]);

  // ---- G1: wave e -> M-tile e&1, N-tile e>>1; dx-mean folded (1/8 into weights) ----
  const int g1mt = e & 1;
  const int g1nt = e >> 1;
  short8 bg1x, bg1f;
  #pragma unroll
  for (int j = 0; j < 8; j++) {
    bg1x[j] = (short)f2b_rn(Gw1[(quad * 8 + j) * HH + g1nt * 16 + l15]);
    bg1f[j] = (short)f2b_rn(0.125f * Gw1[(DD + quad * 8 + j) * HH + g1nt * 16 + l15]);
  }
  const float gb1a = Gb1[g1nt * 16 + l15];

  short8 bg2[2];
  float gb2v = 0.f;
  if (e < 2) {                         // G2: waves 0-1, M-tile = e
    #pragma unroll
    for (int ks = 0; ks < 2; ks++)
      #pragma unroll
      for (int j = 0; j < 8; j++)
        bg2[ks][j] = (short)((l15 < 8) ? f2b_rn(Gw2[(ks * 32 + quad * 8 + j) * EE + l15]) : 0);
    gb2v = (l15 < 8) ? Gb2[l15] : 0.f;
  }

  // per-lane C-init components (col-only), bf16-packed
  u32 c1p[4], c2p[2], c3p;
  #pragma unroll
  for (int nt = 0; nt < 4; nt++)
    c1p[nt] = pack2_rn(b1f[nt * 16 + l15], W1f[DD * HH + nt * 16 + l15]);
  #pragma unroll
  for (int p = 0; p < 2; p++)
    c2p[p] = pack2_rn(b2f[(2 * p) * 16 + l15], b2f[(2 * p + 1) * 16 + l15]);
  c3p = pack2_rn(b3f[l15], b3f[16 + l15]);

  // ---- state init: thread owns dims 2cg..2cg+1 of elem cm ----
  float xst[2], xacc[2];
  {
    const float2 v = *(const float2*)(x0 + cb * DD + 2 * cg);
    xst[0] = v.x; xst[1] = v.y;
    xacc[0] = v.x; xacc[1] = v.y;
    xdb[cm * 20 + cg] = pack2_rn(v.x, v.y);
    *(float2*)(out + cb * TT * DD + 2 * cg) = v;
  }
  __syncthreads();

  u16* const fw16 = (u16*)fsb;               // f, row stride 264 u16
  u16* const us16 = (u16*)usb;               // U, row stride 72 u16

  #pragma unroll 1
  for (int step = 0; step < TT - 1; step++) {
    const float t0 = tspan[step];
    const float t1 = tspan[step + 1];
    const float dt = t1 - t0;

    #pragma unroll 1
    for (int s = 0; s < 4; s++) {
      const float tcur = (s == 0) ? t0 : ((s == 3) ? t1 : t0 + 0.5f * dt);

      f32x4 c1i[4];
      #pragma unroll
      for (int nt = 0; nt < 4; nt++)
        c1i[nt] = bcast4(__builtin_fmaf(tcur, unp_hi(c1p[nt]), unp_lo(c1p[nt])));

      // ========== Phase A: expert MLP via MFMA (2 M-tiles, ping-pong scratch) ==========
      #pragma unroll 2
      for (int mt = 0; mt < 2; mt++) {
        u32* const hw   = hs + e * 1152 + (mt & 1) * 576;   // disjoint region per mt parity
        u16* const hw16 = (u16*)hw;

        const short8 a1 = lds_frag(&xdb[(mt * 16 + l15) * 20 + quad * 4]);
        f32x4 h1a[4];
        #pragma unroll
        for (int nt = 0; nt < 4; nt++)
          h1a[nt] = __builtin_amdgcn_mfma_f32_16x16x32_bf16(a1, bw1[nt], c1i[nt], 0, 0, 0);
        #pragma unroll
        for (int nt = 0; nt < 4; nt++)
          #pragma unroll
          for (int r = 0; r < 4; r++)
            hw16[(quad * 4 + r) * 72 + nt * 16 + l15] = f2b_rn(fast_tanh(h1a[nt][r]));

        f32x4 h2a[4];
        #pragma unroll
        for (int nt = 0; nt < 4; nt++)
          h2a[nt] = bcast4((nt & 1) ? unp_hi(c2p[nt >> 1]) : unp_lo(c2p[nt >> 1]));
        #pragma unroll
        for (int ks = 0; ks < 2; ks++) {
          const short8 a2 = lds_frag(&hw[l15 * 36 + ks * 16 + quad * 4]);
          #pragma unroll
          for (int nt = 0; nt < 4; nt++)
            h2a[nt] = __builtin_amdgcn_mfma_f32_16x16x32_bf16(a2, bw2[ks][nt], h2a[nt], 0, 0, 0);
        }
        #pragma unroll
        for (int nt = 0; nt < 4; nt++)
          #pragma unroll
          for (int r = 0; r < 4; r++)
            hw16[(quad * 4 + r) * 72 + nt * 16 + l15] = f2b_rn(fast_tanh(h2a[nt][r]));

        f32x4 fa[2];
        #pragma unroll
        for (int dt2 = 0; dt2 < 2; dt2++)
          fa[dt2] = bcast4(dt2 ? unp_hi(c3p) : unp_lo(c3p));
        #pragma unroll
        for (int ks = 0; ks < 2; ks++) {
          const short8 a3 = lds_frag(&hw[l15 * 36 + ks * 16 + quad * 4]);
          #pragma unroll
          for (int dt2 = 0; dt2 < 2; dt2++)
            fa[dt2] = __builtin_amdgcn_mfma_f32_16x16x32_bf16(a3, bw3[ks][dt2], fa[dt2], 0, 0, 0);
        }
        #pragma unroll
        for (int dt2 = 0; dt2 < 2; dt2++)
          #pragma unroll
          for (int r = 0; r < 4; r++)
            fw16[(mt * 16 + quad * 4 + r) * 264 + e * 32 + dt2 * 16 + l15] = f2b_rn(fa[dt2][r]);
      } // mt
      __syncthreads();   // fs complete

      // ========== G1: U = tanh(x@Gw1x + (Σ_e f_e)@(Gw1dx/8) + Gb1), 1 (M,N) job/wave ==========
      {
        f32x4 u0 = bcast4(gb1a);
        const int mg = g1mt * 16 + l15;
        const short8 ax = lds_frag(&xdb[mg * 20 + quad * 4]);
        u0 = __builtin_amdgcn_mfma_f32_16x16x32_bf16(ax, bg1x, u0, 0, 0, 0);
        #pragma unroll
        for (int kb = 0; kb < 8; kb++) {
          const short8 af = lds_frag(&fsb[mg * 132 + kb * 16 + quad * 4]);
          u0 = __builtin_amdgcn_mfma_f32_16x16x32_bf16(af, bg1f, u0, 0, 0, 0);
        }
        #pragma unroll
        for (int r = 0; r < 4; r++)
          us16[(g1mt * 16 + quad * 4 + r) * 72 + g1nt * 16 + l15] = f2b_rn(fast_tanh(u0[r]));
      }
      __syncthreads();   // U complete

      // ========== G2: logits = U @ Gw2 + Gb2 (waves 0-1, M-tile = e) ==========
      if (e < 2) {
        f32x4 lv = bcast4(gb2v);
        #pragma unroll
        for (int ks = 0; ks < 2; ks++) {
          const short8 ag = lds_frag(&usb[(e * 16 + l15) * 36 + ks * 16 + quad * 4]);
          lv = __builtin_amdgcn_mfma_f32_16x16x32_bf16(ag, bg2[ks], lv, 0, 0, 0);
        }
        if (l15 < 8) {
          #pragma unroll
          for (int r = 0; r < 4; r++)
            lg[(e * 16 + quad * 4 + r) * 12 + l15] = lv[r];
        }
      }
      __syncthreads();   // logits complete

      // ========== C: softmax (no max-sub; logits bounded) + weighted sum + RK4 ==========
      {
        const float4 la0 = *(const float4*)&lg[cm * 12 + 0];
        const float4 la1 = *(const float4*)&lg[cm * 12 + 4];
        float w8[EE];
        w8[0] = __expf(la0.x); w8[1] = __expf(la0.y);
        w8[2] = __expf(la0.z); w8[3] = __expf(la0.w);
        w8[4] = __expf(la1.x); w8[5] = __expf(la1.y);
        w8[6] = __expf(la1.z); w8[7] = __expf(la1.w);
        float ss = 0.f;
        #pragma unroll
        for (int j = 0; j < EE; j++) ss += w8[j];
        const float inv = __builtin_amdgcn_rcpf(ss);

        float kc[2] = {0.f, 0.f};
        #pragma unroll
        for (int j = 0; j < EE; j++) {
          const float wg = w8[j] * inv;
          const u32 p = fsb[cm * 132 + j * 16 + cg];
          kc[0] = __builtin_fmaf(wg, unp_lo(p), kc[0]);
          kc[1] = __builtin_fmaf(wg, unp_hi(p), kc[1]);
        }

        const float wk = (s == 1 || s == 2) ? 2.f : 1.f;
        const float ak = dt * (1.f / 6.f) * wk;
        #pragma unroll
        for (int q = 0; q < 2; q++) xacc[q] = __builtin_fmaf(ak, kc[q], xacc[q]);

        float xn[2];
        if (s < 3) {
          const float cn = (s == 2) ? dt : 0.5f * dt;
          #pragma unroll
          for (int q = 0; q < 2; q++) xn[q] = __builtin_fmaf(cn, kc[q], xst[q]);
        } else {
          #pragma unroll
          for (int q = 0; q < 2; q++) { xst[q] = xacc[q]; xn[q] = xacc[q]; }
          float2 o; o.x = xn[0]; o.y = xn[1];
          *(float2*)(out + (cb * TT + step + 1) * DD + 2 * cg) = o;
        }
        xdb[cm * 20 + cg] = pack2_rn(xn[0], xn[1]);
      }
      __syncthreads();   // end of stage
    } // stages
  } // steps
}

extern "C" void kernel_launch(void* const* d_in, const int* in_sizes, int n_in,
                              void* d_out, int out_size, void* d_ws, size_t ws_size,
                              hipStream_t stream)
{
  const float* x0    = (const float*)d_in[0];
  const float* tspan = (const float*)d_in[1];
  const float* W1  = (const float*)d_in[2];
  const float* b1  = (const float*)d_in[3];
  const float* W2  = (const float*)d_in[4];
  const float* b2  = (const float*)d_in[5];
  const float* W3  = (const float*)d_in[6];
  const float* b3  = (const float*)d_in[7];
  const float* Gw1 = (const float*)d_in[8];
  const float* Gb1 = (const float*)d_in[9];
  const float* Gw2 = (const float*)d_in[10];
  const float* Gb2 = (const float*)d_in[11];

  // Dynamic-LDS attribute (62.4 KB < 64 KB default, but keep the opt-in:
  // host-side, idempotent, graph-capture safe).
  (void)hipFuncSetAttribute((const void*)ame_ode_kernel,
                            hipFuncAttributeMaxDynamicSharedMemorySize, DYN_LDS);

  ame_ode_kernel<<<BATCH / EPB, 512, DYN_LDS, stream>>>(
      x0, tspan, W1, b1, W2, b2, W3, b3, Gw1, Gb1, Gw2, Gb2, (float*)d_out);
}

// Round 2
// 343.475 us; speedup vs baseline: 1.0242x; 1.0242x over previous
//
#include <hip/hip_runtime.h>
#include <hip/hip_bf16.h>

typedef unsigned int u32;
typedef unsigned short u16;
typedef __attribute__((ext_vector_type(8))) short short8;   // 8 bf16 (4 VGPRs) MFMA A/B frag
typedef __attribute__((ext_vector_type(4))) float f32x4;    // MFMA C/D frag
typedef __attribute__((ext_vector_type(4))) u32 u32x4;
typedef __attribute__((ext_vector_type(2))) u32 u32x2;

#define DD 32
#define EE 8
#define HH 64
#define TT 10
#define BATCH 16384
#define EPB 64          // batch elements per block; grid 256 = 1 block/CU
#define DYN_LDS 75776   // bytes: xdb 5120 + fsb 33792 + hs 36864

#if __has_builtin(__builtin_amdgcn_exp2f)
#define EXP2F(x) __builtin_amdgcn_exp2f(x)
#else
#define EXP2F(x) __builtin_exp2f(x)
#endif

__device__ __forceinline__ float fast_tanh(float x) {
  float e = EXP2F(x * 2.885390082f);
  return 1.f - 2.f * __builtin_amdgcn_rcpf(e + 1.f);
}
__device__ __forceinline__ u16 f2b_rn(float v) {
  return (u16)((__float_as_uint(v) + 0x8000u) >> 16);
}
__device__ __forceinline__ u32 pack2_rn(float a, float b) {
  return __builtin_amdgcn_perm(__float_as_uint(b) + 0x8000u,
                               __float_as_uint(a) + 0x8000u, 0x07060302u);
}
__device__ __forceinline__ float unp_lo(u32 p) { return __uint_as_float(p << 16); }
__device__ __forceinline__ float unp_hi(u32 p) { return __uint_as_float(p & 0xffff0000u); }
__device__ __forceinline__ short8 lds_frag(const u32* p) {
  u32x4 v = *(const u32x4*)p;               // ds_read_b128 (16B-aligned by construction)
  return __builtin_bit_cast(short8, v);
}
__device__ __forceinline__ f32x4 bcast4(float v) { f32x4 c; c[0]=v; c[1]=v; c[2]=v; c[3]=v; return c; }

// wave = expert (8 waves, 512 thr), EPB=64, grid 256 = 1 block/CU (R12 base).
// R15: BARRIERS 4 -> 2 per stage. R14 post-mortem: 2-block/CU co-residency did
// NOT materialize (occupancy stayed 23%) and halved per-wave ILP regressed 13%.
// Instead, gating (G1+G2+softmax+C) is now WAVE-LOCAL: each wave gates its own
// 8 elements (16-row MFMA tile with rows duplicated, Gw1/Gw2 frags replicated
// per wave). After phase A's barrier nothing crosses waves until next stage's
// A reads xdb -> the G1/G2 and G2/C barriers disappear, as do usb/lg buffers.
// U-transpose goes through the per-wave hs scratch (in-wave DS write->read
// ordering — the same proven pattern phase A uses for h). G1 x-part hoisted
// before the barrier (xdb stable during A). VGPR ~180-200 is FREE at
// 1 block/CU: 8 waves = 2 waves/SIMD needs only VGPR<=256. Plain
// __launch_bounds__(512); LDS layouts from R12 kept verbatim (plain
// stride-132 fsb rows; per-wave ping-pong h-scratch).
__global__ __launch_bounds__(512) void ame_ode_kernel(
    const float* __restrict__ x0, const float* __restrict__ tspan,
    const float* __restrict__ W1, const float* __restrict__ b1,
    const float* __restrict__ W2, const float* __restrict__ b2,
    const float* __restrict__ W3, const float* __restrict__ b3,
    const float* __restrict__ Gw1, const float* __restrict__ Gb1,
    const float* __restrict__ Gw2, const float* __restrict__ Gb2,
    float* __restrict__ out)
{
  extern __shared__ __align__(16) u32 dynbuf[];
  u32*  const xdb = dynbuf;                    // [EPB][20] u32: xs bf16x2 (5120 B)
  u32*  const fsb = dynbuf + 1280;             // [EPB][132] u32: f bf16x2, 16B-aligned rows (33792 B)
  u32*  const hs  = dynbuf + 9728;             // [8 waves][2 regions][16][36] u32 scratch (36864 B)

  const int tid  = threadIdx.x;
  const int lane = tid & 63;
  const int l15  = lane & 15;
  const int quad = lane >> 4;
  const int e    = __builtin_amdgcn_readfirstlane(tid >> 6);   // wave-uniform expert id

  // gating/C mapping: wave e owns elements 8e..8e+7; lane -> (el, dim group q8)
  const int el = lane >> 3;                    // element within wave's 8
  const int q8 = lane & 7;                     // dim-quad index (dims 4*q8..4*q8+3)
  const int gr = e * 8 + el;                   // block-local gated row
  const int gb = blockIdx.x * EPB + gr;        // global batch element

  const float* W1f = W1 + e * (DD + 1) * HH;
  const float* b1f = b1 + e * HH;
  const float* W2f = W2 + e * HH * HH;
  const float* b2f = b2 + e * HH;
  const float* W3f = W3 + e * HH * DD;
  const float* b3f = b3 + e * DD;

  // ---- expert-weight B-frags: B[k=quad*8+j][n=l15(+16nt)] ----
  short8 bw1[4], bw2[2][4], bw3[2][2];
  #pragma unroll
  for (int nt = 0; nt < 4; nt++)
    #pragma unroll
    for (int j = 0; j < 8; j++)
      bw1[nt][j] = (short)f2b_rn(W1f[(quad * 8 + j) * HH + nt * 16 + l15]);
  #pragma unroll
  for (int ks = 0; ks < 2; ks++)
    #pragma unroll
    for (int nt = 0; nt < 4; nt++)
      #pragma unroll
      for (int j = 0; j < 8; j++)
        bw2[ks][nt][j] = (short)f2b_rn(W2f[(ks * 32 + quad * 8 + j) * HH + nt * 16 + l15]);
  #pragma unroll
  for (int ks = 0; ks < 2; ks++)
    #pragma unroll
    for (int dt2 = 0; dt2 < 2; dt2++)
      #pragma unroll
      for (int j = 0; j < 8; j++)
        bw3[ks][dt2][j] = (short)f2b_rn(W3f[(ks * 32 + quad * 8 + j) * DD + dt2 * 16 + l15]);

  // ---- G1 weights, FULL N=64 per wave (replicated); dx-mean 1/8 folded ----
  short8 bg1x[4], bg1f[4];
  float gb1v[4];
  #pragma unroll
  for (int nt = 0; nt < 4; nt++) {
    #pragma unroll
    for (int j = 0; j < 8; j++) {
      bg1x[nt][j] = (short)f2b_rn(Gw1[(quad * 8 + j) * HH + nt * 16 + l15]);
      bg1f[nt][j] = (short)f2b_rn(0.125f * Gw1[(DD + quad * 8 + j) * HH + nt * 16 + l15]);
    }
    gb1v[nt] = Gb1[nt * 16 + l15];
  }

  // ---- G2 weights, replicated to every wave ----
  short8 bg2[2];
  #pragma unroll
  for (int ks = 0; ks < 2; ks++)
    #pragma unroll
    for (int j = 0; j < 8; j++)
      bg2[ks][j] = (short)((l15 < 8) ? f2b_rn(Gw2[(ks * 32 + quad * 8 + j) * EE + l15]) : 0);
  const float gb2v = (l15 < 8) ? Gb2[l15] : 0.f;

  // per-lane C-init components (col-only), bf16-packed
  u32 c1p[4], c2p[2], c3p;
  #pragma unroll
  for (int nt = 0; nt < 4; nt++)
    c1p[nt] = pack2_rn(b1f[nt * 16 + l15], W1f[DD * HH + nt * 16 + l15]);
  #pragma unroll
  for (int p = 0; p < 2; p++)
    c2p[p] = pack2_rn(b2f[(2 * p) * 16 + l15], b2f[(2 * p + 1) * 16 + l15]);
  c3p = pack2_rn(b3f[l15], b3f[16 + l15]);

  // ---- state init: lane owns dims 4*q8..4*q8+3 of element gr ----
  float xst[4], xacc[4];
  {
    const float4 v = *(const float4*)(x0 + gb * DD + q8 * 4);
    xst[0] = v.x; xst[1] = v.y; xst[2] = v.z; xst[3] = v.w;
    xacc[0] = v.x; xacc[1] = v.y; xacc[2] = v.z; xacc[3] = v.w;
    u32x2 p; p.x = pack2_rn(v.x, v.y); p.y = pack2_rn(v.z, v.w);
    *(u32x2*)&xdb[gr * 20 + q8 * 2] = p;
    *(float4*)(out + gb * TT * DD + q8 * 4) = v;
  }
  __syncthreads();

  u16*  const fw16 = (u16*)fsb;              // f, row stride 264 u16
  u32*  const hsw  = hs + e * 1152;          // this wave's scratch (2 regions of 576 u32)
  u16*  const uw16 = (u16*)hsw;              // U scratch lives in region 0 during G
  float* const wscr = (float*)(hsw + 576);   // softmax weights [8 elem][8 expert] in region 1

  #pragma unroll 1
  for (int step = 0; step < TT - 1; step++) {
    const float t0 = tspan[step];
    const float t1 = tspan[step + 1];
    const float dt = t1 - t0;

    #pragma unroll 1
    for (int s = 0; s < 4; s++) {
      const float tcur = (s == 0) ? t0 : ((s == 3) ? t1 : t0 + 0.5f * dt);

      f32x4 c1i[4];
      #pragma unroll
      for (int nt = 0; nt < 4; nt++)
        c1i[nt] = bcast4(__builtin_fmaf(tcur, unp_hi(c1p[nt]), unp_lo(c1p[nt])));

      // ========== Phase A: expert MLP via MFMA (4 M-tiles, ping-pong scratch) ==========
      #pragma unroll 2
      for (int mt = 0; mt < 4; mt++) {
        u32* const hw   = hsw + (mt & 1) * 576;   // disjoint region per mt parity
        u16* const hw16 = (u16*)hw;

        const short8 a1 = lds_frag(&xdb[(mt * 16 + l15) * 20 + quad * 4]);
        f32x4 h1a[4];
        #pragma unroll
        for (int nt = 0; nt < 4; nt++)
          h1a[nt] = __builtin_amdgcn_mfma_f32_16x16x32_bf16(a1, bw1[nt], c1i[nt], 0, 0, 0);
        #pragma unroll
        for (int nt = 0; nt < 4; nt++)
          #pragma unroll
          for (int r = 0; r < 4; r++)
            hw16[(quad * 4 + r) * 72 + nt * 16 + l15] = f2b_rn(fast_tanh(h1a[nt][r]));

        f32x4 h2a[4];
        #pragma unroll
        for (int nt = 0; nt < 4; nt++)
          h2a[nt] = bcast4((nt & 1) ? unp_hi(c2p[nt >> 1]) : unp_lo(c2p[nt >> 1]));
        #pragma unroll
        for (int ks = 0; ks < 2; ks++) {
          const short8 a2 = lds_frag(&hw[l15 * 36 + ks * 16 + quad * 4]);
          #pragma unroll
          for (int nt = 0; nt < 4; nt++)
            h2a[nt] = __builtin_amdgcn_mfma_f32_16x16x32_bf16(a2, bw2[ks][nt], h2a[nt], 0, 0, 0);
        }
        #pragma unroll
        for (int nt = 0; nt < 4; nt++)
          #pragma unroll
          for (int r = 0; r < 4; r++)
            hw16[(quad * 4 + r) * 72 + nt * 16 + l15] = f2b_rn(fast_tanh(h2a[nt][r]));

        f32x4 fa[2];
        #pragma unroll
        for (int dt2 = 0; dt2 < 2; dt2++)
          fa[dt2] = bcast4(dt2 ? unp_hi(c3p) : unp_lo(c3p));
        #pragma unroll
        for (int ks = 0; ks < 2; ks++) {
          const short8 a3 = lds_frag(&hw[l15 * 36 + ks * 16 + quad * 4]);
          #pragma unroll
          for (int dt2 = 0; dt2 < 2; dt2++)
            fa[dt2] = __builtin_amdgcn_mfma_f32_16x16x32_bf16(a3, bw3[ks][dt2], fa[dt2], 0, 0, 0);
        }
        #pragma unroll
        for (int dt2 = 0; dt2 < 2; dt2++)
          #pragma unroll
          for (int r = 0; r < 4; r++)
            fw16[(mt * 16 + quad * 4 + r) * 264 + e * 32 + dt2 * 16 + l15] = f2b_rn(fa[dt2][r]);
      } // mt

      // ---- G1 x-part hoisted before the barrier (xdb stable during phase A) ----
      f32x4 u4[4];
      {
        const short8 ax = lds_frag(&xdb[(e * 8 + (l15 & 7)) * 20 + quad * 4]);
        #pragma unroll
        for (int nt = 0; nt < 4; nt++)
          u4[nt] = __builtin_amdgcn_mfma_f32_16x16x32_bf16(ax, bg1x[nt], bcast4(gb1v[nt]), 0, 0, 0);
      }
      __syncthreads();   // fsb complete — ONLY cross-wave handoff until next A

      // ========== G (wave-local): U -> logits -> softmax -> weighted sum -> RK4 ==========
      // G1 f-part: K-blocks = 8 experts' f (dx-mean folded), A rows = own 8 elems dup'd
      #pragma unroll
      for (int kb = 0; kb < 8; kb++) {
        const short8 af = lds_frag(&fsb[(e * 8 + (l15 & 7)) * 132 + kb * 16 + quad * 4]);
        #pragma unroll
        for (int nt = 0; nt < 4; nt++)
          u4[nt] = __builtin_amdgcn_mfma_f32_16x16x32_bf16(af, bg1f[nt], u4[nt], 0, 0, 0);
      }
      // tanh + transpose through per-wave scratch (in-wave DS order, no barrier)
      #pragma unroll
      for (int nt = 0; nt < 4; nt++)
        #pragma unroll
        for (int r = 0; r < 4; r++)
          uw16[(quad * 4 + r) * 72 + nt * 16 + l15] = f2b_rn(fast_tanh(u4[nt][r]));

      // G2: logits = U @ Gw2 + Gb2 (cols l15<8 valid)
      f32x4 lv = bcast4(gb2v);
      #pragma unroll
      for (int ks = 0; ks < 2; ks++) {
        const short8 ag = lds_frag(&hsw[l15 * 36 + ks * 16 + quad * 4]);
        lv = __builtin_amdgcn_mfma_f32_16x16x32_bf16(ag, bg2[ks], lv, 0, 0, 0);
      }

      // softmax across 8 expert lanes (l15 0..7), per accumulator row r
      float wgt[4];
      #pragma unroll
      for (int r = 0; r < 4; r++) {
        const float p = __expf(lv[r]);             // logits bounded; no max-sub (validated)
        float ssum = p + __shfl_xor(p, 1);
        ssum += __shfl_xor(ssum, 2);
        ssum += __shfl_xor(ssum, 4);
        wgt[r] = p * __builtin_amdgcn_rcpf(ssum);
      }
      // scatter weights to region-1 scratch: rows m=0..7 (quads 0,1), cols j=l15
      if (quad < 2 && l15 < 8) {
        #pragma unroll
        for (int r = 0; r < 4; r++)
          wscr[(quad * 4 + r) * 8 + l15] = wgt[r];
      }
      // gather own element's 8 weights (broadcast reads, 2x b128)
      const f32x4 w0 = *(const f32x4*)&wscr[el * 8];
      const f32x4 w1 = *(const f32x4*)&wscr[el * 8 + 4];

      // weighted sum over experts for dims 4*q8..4*q8+3 of element gr
      float kc[4] = {0.f, 0.f, 0.f, 0.f};
      #pragma unroll
      for (int j = 0; j < EE; j++) {
        const float wg = (j < 4) ? w0[j] : w1[j - 4];
        const u32x2 pf = *(const u32x2*)&fsb[gr * 132 + j * 16 + q8 * 2];
        kc[0] = __builtin_fmaf(wg, unp_lo(pf.x), kc[0]);
        kc[1] = __builtin_fmaf(wg, unp_hi(pf.x), kc[1]);
        kc[2] = __builtin_fmaf(wg, unp_lo(pf.y), kc[2]);
        kc[3] = __builtin_fmaf(wg, unp_hi(pf.y), kc[3]);
      }

      const float wk = (s == 1 || s == 2) ? 2.f : 1.f;
      const float ak = dt * (1.f / 6.f) * wk;
      #pragma unroll
      for (int q = 0; q < 4; q++) xacc[q] = __builtin_fmaf(ak, kc[q], xacc[q]);

      float xn[4];
      if (s < 3) {
        const float cn = (s == 2) ? dt : 0.5f * dt;
        #pragma unroll
        for (int q = 0; q < 4; q++) xn[q] = __builtin_fmaf(cn, kc[q], xst[q]);
      } else {
        #pragma unroll
        for (int q = 0; q < 4; q++) { xst[q] = xacc[q]; xn[q] = xacc[q]; }
        float4 o; o.x = xn[0]; o.y = xn[1]; o.z = xn[2]; o.w = xn[3];
        *(float4*)(out + (gb * TT + step + 1) * DD + q8 * 4) = o;
      }
      u32x2 p; p.x = pack2_rn(xn[0], xn[1]); p.y = pack2_rn(xn[2], xn[3]);
      *(u32x2*)&xdb[gr * 20 + q8 * 2] = p;

      __syncthreads();   // xdb complete for next stage's phase A
    } // stages
  } // steps
}

extern "C" void kernel_launch(void* const* d_in, const int* in_sizes, int n_in,
                              void* d_out, int out_size, void* d_ws, size_t ws_size,
                              hipStream_t stream)
{
  const float* x0    = (const float*)d_in[0];
  const float* tspan = (const float*)d_in[1];
  const float* W1  = (const float*)d_in[2];
  const float* b1  = (const float*)d_in[3];
  const float* W2  = (const float*)d_in[4];
  const float* b2  = (const float*)d_in[5];
  const float* W3  = (const float*)d_in[6];
  const float* b3  = (const float*)d_in[7];
  const float* Gw1 = (const float*)d_in[8];
  const float* Gb1 = (const float*)d_in[9];
  const float* Gw2 = (const float*)d_in[10];
  const float* Gb2 = (const float*)d_in[11];

  // Opt in to >64 KB dynamic LDS (160 KB/CU on gfx950). Host-side, idempotent,
  // graph-capture safe. Called unconditionally every launch.
  (void)hipFuncSetAttribute((const void*)ame_ode_kernel,
                            hipFuncAttributeMaxDynamicSharedMemorySize, DYN_LDS);

  ame_ode_kernel<<<BATCH / EPB, 512, DYN_LDS, stream>>>(
      x0, tspan, W1, b1, W2, b2, W3, b3, Gw1, Gb1, Gw2, Gb2, (float*)d_out);
}

// Round 3
// 341.051 us; speedup vs baseline: 1.0315x; 1.0071x over previous
//
#include <hip/hip_runtime.h>
#include <hip/hip_bf16.h>

typedef unsigned int u32;
typedef unsigned short u16;
typedef __attribute__((ext_vector_type(8))) short short8;   // 8 bf16 (4 VGPRs) MFMA A/B frag
typedef __attribute__((ext_vector_type(4))) float f32x4;    // MFMA C/D frag
typedef __attribute__((ext_vector_type(4))) u32 u32x4;
typedef __attribute__((ext_vector_type(2))) u32 u32x2;

#define DD 32
#define EE 8
#define HH 64
#define TT 10
#define BATCH 16384
#define EPB 64          // batch elements per block; grid 256 = 1 block/CU
#define DYN_LDS 75776   // bytes: xdb 5120 + fsb 33792 + hs 36864

#if __has_builtin(__builtin_amdgcn_exp2f)
#define EXP2F(x) __builtin_amdgcn_exp2f(x)
#else
#define EXP2F(x) __builtin_exp2f(x)
#endif

__device__ __forceinline__ float fast_tanh(float x) {
  float e = EXP2F(x * 2.885390082f);
  return 1.f - 2.f * __builtin_amdgcn_rcpf(e + 1.f);
}
__device__ __forceinline__ u16 f2b_rn(float v) {
  return (u16)((__float_as_uint(v) + 0x8000u) >> 16);
}
__device__ __forceinline__ u32 pack2_rn(float a, float b) {
  return __builtin_amdgcn_perm(__float_as_uint(b) + 0x8000u,
                               __float_as_uint(a) + 0x8000u, 0x07060302u);
}
__device__ __forceinline__ float unp_lo(u32 p) { return __uint_as_float(p << 16); }
__device__ __forceinline__ float unp_hi(u32 p) { return __uint_as_float(p & 0xffff0000u); }
__device__ __forceinline__ short8 lds_frag(const u32* p) {
  u32x4 v = *(const u32x4*)p;               // ds_read_b128 (16B-aligned by construction)
  return __builtin_bit_cast(short8, v);
}
__device__ __forceinline__ f32x4 bcast4(float v) { f32x4 c; c[0]=v; c[1]=v; c[2]=v; c[3]=v; return c; }

// wave = expert (8 waves, 512 thr), EPB=64, grid 256 = 1 block/CU.
// R16 = R15 (wave-local gating, 2 barriers/stage) + __launch_bounds__(512, 2).
// R15 post-mortem: structure was sound but compiler capped VGPR at 128 (default
// waves/EU heuristic) and SPILLED ~22 regs/thread (WRITE 20.5->32.3 MB,
// FETCH 2.25->7.7 MB = scratch traffic; ~800 scratch reloads/thread in-loop).
// HW law (m69): VGPR pool = 512/SIMD; at our residency (one 512-thr block/CU
// = 2 waves/SIMD) each wave may use 256 VGPR. launch_bounds 2nd arg = min
// waves/EU = 2 -> VGPR cap 256 -> replicated gating weights stay in registers.
// (Earlier session's "caps <=128 spill" warning was about args implying >=4
// waves/EU.) Gating (G1+G2+softmax+C) is WAVE-LOCAL: each wave gates its own
// 8 elements (16-row MFMA tile, rows dup'd; Gw1/Gw2 frags replicated). After
// phase A's barrier nothing crosses waves until next stage's A reads xdb ->
// 2 barriers/stage. U-transpose via per-wave hs scratch (in-wave DS order).
// G1 x-part hoisted before the barrier (xdb stable during A). LDS layouts
// from R12 verbatim (stride-132 fsb rows; ping-pong h-scratch).
__global__ __launch_bounds__(512, 2) void ame_ode_kernel(
    const float* __restrict__ x0, const float* __restrict__ tspan,
    const float* __restrict__ W1, const float* __restrict__ b1,
    const float* __restrict__ W2, const float* __restrict__ b2,
    const float* __restrict__ W3, const float* __restrict__ b3,
    const float* __restrict__ Gw1, const float* __restrict__ Gb1,
    const float* __restrict__ Gw2, const float* __restrict__ Gb2,
    float* __restrict__ out)
{
  extern __shared__ __align__(16) u32 dynbuf[];
  u32*  const xdb = dynbuf;                    // [EPB][20] u32: xs bf16x2 (5120 B)
  u32*  const fsb = dynbuf + 1280;             // [EPB][132] u32: f bf16x2, 16B-aligned rows (33792 B)
  u32*  const hs  = dynbuf + 9728;             // [8 waves][2 regions][16][36] u32 scratch (36864 B)

  const int tid  = threadIdx.x;
  const int lane = tid & 63;
  const int l15  = lane & 15;
  const int quad = lane >> 4;
  const int e    = __builtin_amdgcn_readfirstlane(tid >> 6);   // wave-uniform expert id

  // gating/C mapping: wave e owns elements 8e..8e+7; lane -> (el, dim group q8)
  const int el = lane >> 3;                    // element within wave's 8
  const int q8 = lane & 7;                     // dim-quad index (dims 4*q8..4*q8+3)
  const int gr = e * 8 + el;                   // block-local gated row
  const int gb = blockIdx.x * EPB + gr;        // global batch element

  const float* W1f = W1 + e * (DD + 1) * HH;
  const float* b1f = b1 + e * HH;
  const float* W2f = W2 + e * HH * HH;
  const float* b2f = b2 + e * HH;
  const float* W3f = W3 + e * HH * DD;
  const float* b3f = b3 + e * DD;

  // ---- expert-weight B-frags: B[k=quad*8+j][n=l15(+16nt)] ----
  short8 bw1[4], bw2[2][4], bw3[2][2];
  #pragma unroll
  for (int nt = 0; nt < 4; nt++)
    #pragma unroll
    for (int j = 0; j < 8; j++)
      bw1[nt][j] = (short)f2b_rn(W1f[(quad * 8 + j) * HH + nt * 16 + l15]);
  #pragma unroll
  for (int ks = 0; ks < 2; ks++)
    #pragma unroll
    for (int nt = 0; nt < 4; nt++)
      #pragma unroll
      for (int j = 0; j < 8; j++)
        bw2[ks][nt][j] = (short)f2b_rn(W2f[(ks * 32 + quad * 8 + j) * HH + nt * 16 + l15]);
  #pragma unroll
  for (int ks = 0; ks < 2; ks++)
    #pragma unroll
    for (int dt2 = 0; dt2 < 2; dt2++)
      #pragma unroll
      for (int j = 0; j < 8; j++)
        bw3[ks][dt2][j] = (short)f2b_rn(W3f[(ks * 32 + quad * 8 + j) * DD + dt2 * 16 + l15]);

  // ---- G1 weights, FULL N=64 per wave (replicated); dx-mean 1/8 folded ----
  short8 bg1x[4], bg1f[4];
  float gb1v[4];
  #pragma unroll
  for (int nt = 0; nt < 4; nt++) {
    #pragma unroll
    for (int j = 0; j < 8; j++) {
      bg1x[nt][j] = (short)f2b_rn(Gw1[(quad * 8 + j) * HH + nt * 16 + l15]);
      bg1f[nt][j] = (short)f2b_rn(0.125f * Gw1[(DD + quad * 8 + j) * HH + nt * 16 + l15]);
    }
    gb1v[nt] = Gb1[nt * 16 + l15];
  }

  // ---- G2 weights, replicated to every wave ----
  short8 bg2[2];
  #pragma unroll
  for (int ks = 0; ks < 2; ks++)
    #pragma unroll
    for (int j = 0; j < 8; j++)
      bg2[ks][j] = (short)((l15 < 8) ? f2b_rn(Gw2[(ks * 32 + quad * 8 + j) * EE + l15]) : 0);
  const float gb2v = (l15 < 8) ? Gb2[l15] : 0.f;

  // per-lane C-init components (col-only), bf16-packed
  u32 c1p[4], c2p[2], c3p;
  #pragma unroll
  for (int nt = 0; nt < 4; nt++)
    c1p[nt] = pack2_rn(b1f[nt * 16 + l15], W1f[DD * HH + nt * 16 + l15]);
  #pragma unroll
  for (int p = 0; p < 2; p++)
    c2p[p] = pack2_rn(b2f[(2 * p) * 16 + l15], b2f[(2 * p + 1) * 16 + l15]);
  c3p = pack2_rn(b3f[l15], b3f[16 + l15]);

  // ---- state init: lane owns dims 4*q8..4*q8+3 of element gr ----
  float xst[4], xacc[4];
  {
    const float4 v = *(const float4*)(x0 + gb * DD + q8 * 4);
    xst[0] = v.x; xst[1] = v.y; xst[2] = v.z; xst[3] = v.w;
    xacc[0] = v.x; xacc[1] = v.y; xacc[2] = v.z; xacc[3] = v.w;
    u32x2 p; p.x = pack2_rn(v.x, v.y); p.y = pack2_rn(v.z, v.w);
    *(u32x2*)&xdb[gr * 20 + q8 * 2] = p;
    *(float4*)(out + gb * TT * DD + q8 * 4) = v;
  }
  __syncthreads();

  u16*  const fw16 = (u16*)fsb;              // f, row stride 264 u16
  u32*  const hsw  = hs + e * 1152;          // this wave's scratch (2 regions of 576 u32)
  u16*  const uw16 = (u16*)hsw;              // U scratch lives in region 0 during G
  float* const wscr = (float*)(hsw + 576);   // softmax weights [8 elem][8 expert] in region 1

  #pragma unroll 1
  for (int step = 0; step < TT - 1; step++) {
    const float t0 = tspan[step];
    const float t1 = tspan[step + 1];
    const float dt = t1 - t0;

    #pragma unroll 1
    for (int s = 0; s < 4; s++) {
      const float tcur = (s == 0) ? t0 : ((s == 3) ? t1 : t0 + 0.5f * dt);

      f32x4 c1i[4];
      #pragma unroll
      for (int nt = 0; nt < 4; nt++)
        c1i[nt] = bcast4(__builtin_fmaf(tcur, unp_hi(c1p[nt]), unp_lo(c1p[nt])));

      // ========== Phase A: expert MLP via MFMA (4 M-tiles, ping-pong scratch) ==========
      #pragma unroll 2
      for (int mt = 0; mt < 4; mt++) {
        u32* const hw   = hsw + (mt & 1) * 576;   // disjoint region per mt parity
        u16* const hw16 = (u16*)hw;

        const short8 a1 = lds_frag(&xdb[(mt * 16 + l15) * 20 + quad * 4]);
        f32x4 h1a[4];
        #pragma unroll
        for (int nt = 0; nt < 4; nt++)
          h1a[nt] = __builtin_amdgcn_mfma_f32_16x16x32_bf16(a1, bw1[nt], c1i[nt], 0, 0, 0);
        #pragma unroll
        for (int nt = 0; nt < 4; nt++)
          #pragma unroll
          for (int r = 0; r < 4; r++)
            hw16[(quad * 4 + r) * 72 + nt * 16 + l15] = f2b_rn(fast_tanh(h1a[nt][r]));

        f32x4 h2a[4];
        #pragma unroll
        for (int nt = 0; nt < 4; nt++)
          h2a[nt] = bcast4((nt & 1) ? unp_hi(c2p[nt >> 1]) : unp_lo(c2p[nt >> 1]));
        #pragma unroll
        for (int ks = 0; ks < 2; ks++) {
          const short8 a2 = lds_frag(&hw[l15 * 36 + ks * 16 + quad * 4]);
          #pragma unroll
          for (int nt = 0; nt < 4; nt++)
            h2a[nt] = __builtin_amdgcn_mfma_f32_16x16x32_bf16(a2, bw2[ks][nt], h2a[nt], 0, 0, 0);
        }
        #pragma unroll
        for (int nt = 0; nt < 4; nt++)
          #pragma unroll
          for (int r = 0; r < 4; r++)
            hw16[(quad * 4 + r) * 72 + nt * 16 + l15] = f2b_rn(fast_tanh(h2a[nt][r]));

        f32x4 fa[2];
        #pragma unroll
        for (int dt2 = 0; dt2 < 2; dt2++)
          fa[dt2] = bcast4(dt2 ? unp_hi(c3p) : unp_lo(c3p));
        #pragma unroll
        for (int ks = 0; ks < 2; ks++) {
          const short8 a3 = lds_frag(&hw[l15 * 36 + ks * 16 + quad * 4]);
          #pragma unroll
          for (int dt2 = 0; dt2 < 2; dt2++)
            fa[dt2] = __builtin_amdgcn_mfma_f32_16x16x32_bf16(a3, bw3[ks][dt2], fa[dt2], 0, 0, 0);
        }
        #pragma unroll
        for (int dt2 = 0; dt2 < 2; dt2++)
          #pragma unroll
          for (int r = 0; r < 4; r++)
            fw16[(mt * 16 + quad * 4 + r) * 264 + e * 32 + dt2 * 16 + l15] = f2b_rn(fa[dt2][r]);
      } // mt

      // ---- G1 x-part hoisted before the barrier (xdb stable during phase A) ----
      f32x4 u4[4];
      {
        const short8 ax = lds_frag(&xdb[(e * 8 + (l15 & 7)) * 20 + quad * 4]);
        #pragma unroll
        for (int nt = 0; nt < 4; nt++)
          u4[nt] = __builtin_amdgcn_mfma_f32_16x16x32_bf16(ax, bg1x[nt], bcast4(gb1v[nt]), 0, 0, 0);
      }
      __syncthreads();   // fsb complete — ONLY cross-wave handoff until next A

      // ========== G (wave-local): U -> logits -> softmax -> weighted sum -> RK4 ==========
      // G1 f-part: K-blocks = 8 experts' f (dx-mean folded), A rows = own 8 elems dup'd
      #pragma unroll
      for (int kb = 0; kb < 8; kb++) {
        const short8 af = lds_frag(&fsb[(e * 8 + (l15 & 7)) * 132 + kb * 16 + quad * 4]);
        #pragma unroll
        for (int nt = 0; nt < 4; nt++)
          u4[nt] = __builtin_amdgcn_mfma_f32_16x16x32_bf16(af, bg1f[nt], u4[nt], 0, 0, 0);
      }
      // tanh + transpose through per-wave scratch (in-wave DS order, no barrier)
      #pragma unroll
      for (int nt = 0; nt < 4; nt++)
        #pragma unroll
        for (int r = 0; r < 4; r++)
          uw16[(quad * 4 + r) * 72 + nt * 16 + l15] = f2b_rn(fast_tanh(u4[nt][r]));

      // G2: logits = U @ Gw2 + Gb2 (cols l15<8 valid)
      f32x4 lv = bcast4(gb2v);
      #pragma unroll
      for (int ks = 0; ks < 2; ks++) {
        const short8 ag = lds_frag(&hsw[l15 * 36 + ks * 16 + quad * 4]);
        lv = __builtin_amdgcn_mfma_f32_16x16x32_bf16(ag, bg2[ks], lv, 0, 0, 0);
      }

      // softmax across 8 expert lanes (l15 0..7), per accumulator row r
      float wgt[4];
      #pragma unroll
      for (int r = 0; r < 4; r++) {
        const float p = __expf(lv[r]);             // logits bounded; no max-sub (validated)
        float ssum = p + __shfl_xor(p, 1);
        ssum += __shfl_xor(ssum, 2);
        ssum += __shfl_xor(ssum, 4);
        wgt[r] = p * __builtin_amdgcn_rcpf(ssum);
      }
      // scatter weights to region-1 scratch: rows m=0..7 (quads 0,1), cols j=l15
      if (quad < 2 && l15 < 8) {
        #pragma unroll
        for (int r = 0; r < 4; r++)
          wscr[(quad * 4 + r) * 8 + l15] = wgt[r];
      }
      // gather own element's 8 weights (broadcast reads, 2x b128)
      const f32x4 w0 = *(const f32x4*)&wscr[el * 8];
      const f32x4 w1 = *(const f32x4*)&wscr[el * 8 + 4];

      // weighted sum over experts for dims 4*q8..4*q8+3 of element gr
      float kc[4] = {0.f, 0.f, 0.f, 0.f};
      #pragma unroll
      for (int j = 0; j < EE; j++) {
        const float wg = (j < 4) ? w0[j] : w1[j - 4];
        const u32x2 pf = *(const u32x2*)&fsb[gr * 132 + j * 16 + q8 * 2];
        kc[0] = __builtin_fmaf(wg, unp_lo(pf.x), kc[0]);
        kc[1] = __builtin_fmaf(wg, unp_hi(pf.x), kc[1]);
        kc[2] = __builtin_fmaf(wg, unp_lo(pf.y), kc[2]);
        kc[3] = __builtin_fmaf(wg, unp_hi(pf.y), kc[3]);
      }

      const float wk = (s == 1 || s == 2) ? 2.f : 1.f;
      const float ak = dt * (1.f / 6.f) * wk;
      #pragma unroll
      for (int q = 0; q < 4; q++) xacc[q] = __builtin_fmaf(ak, kc[q], xacc[q]);

      float xn[4];
      if (s < 3) {
        const float cn = (s == 2) ? dt : 0.5f * dt;
        #pragma unroll
        for (int q = 0; q < 4; q++) xn[q] = __builtin_fmaf(cn, kc[q], xst[q]);
      } else {
        #pragma unroll
        for (int q = 0; q < 4; q++) { xst[q] = xacc[q]; xn[q] = xacc[q]; }
        float4 o; o.x = xn[0]; o.y = xn[1]; o.z = xn[2]; o.w = xn[3];
        *(float4*)(out + (gb * TT + step + 1) * DD + q8 * 4) = o;
      }
      u32x2 p; p.x = pack2_rn(xn[0], xn[1]); p.y = pack2_rn(xn[2], xn[3]);
      *(u32x2*)&xdb[gr * 20 + q8 * 2] = p;

      __syncthreads();   // xdb complete for next stage's phase A
    } // stages
  } // steps
}

extern "C" void kernel_launch(void* const* d_in, const int* in_sizes, int n_in,
                              void* d_out, int out_size, void* d_ws, size_t ws_size,
                              hipStream_t stream)
{
  const float* x0    = (const float*)d_in[0];
  const float* tspan = (const float*)d_in[1];
  const float* W1  = (const float*)d_in[2];
  const float* b1  = (const float*)d_in[3];
  const float* W2  = (const float*)d_in[4];
  const float* b2  = (const float*)d_in[5];
  const float* W3  = (const float*)d_in[6];
  const float* b3  = (const float*)d_in[7];
  const float* Gw1 = (const float*)d_in[8];
  const float* Gb1 = (const float*)d_in[9];
  const float* Gw2 = (const float*)d_in[10];
  const float* Gb2 = (const float*)d_in[11];

  // Opt in to >64 KB dynamic LDS (160 KB/CU on gfx950). Host-side, idempotent,
  // graph-capture safe. Called unconditionally every launch.
  (void)hipFuncSetAttribute((const void*)ame_ode_kernel,
                            hipFuncAttributeMaxDynamicSharedMemorySize, DYN_LDS);

  ame_ode_kernel<<<BATCH / EPB, 512, DYN_LDS, stream>>>(
      x0, tspan, W1, b1, W2, b2, W3, b3, Gw1, Gb1, Gw2, Gb2, (float*)d_out);
}

// Round 5
// 335.696 us; speedup vs baseline: 1.0480x; 1.0160x over previous
//
#include <hip/hip_runtime.h>
#include <hip/hip_bf16.h>

typedef unsigned int u32;
typedef unsigned short u16;
typedef __attribute__((ext_vector_type(8))) short short8;   // 8 bf16 (4 VGPRs) MFMA A/B frag
typedef __attribute__((ext_vector_type(4))) float f32x4;    // MFMA C/D frag
typedef __attribute__((ext_vector_type(4))) u32 u32x4;
typedef __attribute__((ext_vector_type(2))) u32 u32x2;

#define DD 32
#define EE 8
#define HH 64
#define TT 10
#define BATCH 16384
#define EPB 64          // batch elements per block (grid 256 = 1 block/CU)
#define DYN_LDS 82944   // bytes: xdb 5120 + fsb 33792 + lg 3072 + ust 8192 + hs 32768

#define LDS_AS __attribute__((address_space(3)))

#if __has_builtin(__builtin_amdgcn_exp2f)
#define EXP2F(x) __builtin_amdgcn_exp2f(x)
#else
#define EXP2F(x) __builtin_exp2f(x)
#endif

__device__ __forceinline__ float fast_tanh(float x) {
  float e = EXP2F(x * 2.885390082f);
  return 1.f - 2.f * __builtin_amdgcn_rcpf(e + 1.f);
}
__device__ __forceinline__ u16 f2b_rn(float v) {
  return (u16)((__float_as_uint(v) + 0x8000u) >> 16);
}
__device__ __forceinline__ u32 pack2_rn(float a, float b) {
  return __builtin_amdgcn_perm(__float_as_uint(b) + 0x8000u,
                               __float_as_uint(a) + 0x8000u, 0x07060302u);
}
__device__ __forceinline__ float unp_lo(u32 p) { return __uint_as_float(p << 16); }
__device__ __forceinline__ float unp_hi(u32 p) { return __uint_as_float(p & 0xffff0000u); }
__device__ __forceinline__ short8 lds_frag(const u32* p) {
  u32x4 v = *(const u32x4*)p;               // ds_read_b128 (16B-aligned by construction)
  return __builtin_bit_cast(short8, v);
}
__device__ __forceinline__ f32x4 bcast4(float v) { f32x4 c; c[0]=v; c[1]=v; c[2]=v; c[3]=v; return c; }

// ds_read_b64_tr_b16 crossbar model (m156 formula re-derived): each lane
// fetches 64 contiguous bits at ITS address; the 16-lane group's fetches, in
// lane order, form a 4x16 row-major u16 tile; lane l receives column (l&15).
// So lane L must pass addr = tile_base + (L&15)*4 u16 (8 B/lane, contiguous).
// R17's bug: passed +(L&15) u16 -> wrong chunks -> absmax 1.38. Fixed here.
// Issue-only asm (no per-read drain); caller batches one lgkmcnt(0) +
// sched_barrier(0) (rule #18) before consuming.
__device__ __forceinline__ u32x2 tr_issue(const u16* p) {
  u32x2 d;
  asm volatile("ds_read_b64_tr_b16 %0, %1"
               : "=v"(d)
               : "v"((u32)(uintptr_t)(LDS_AS const u16*)p)
               : "memory");
  return d;
}
__device__ __forceinline__ void lgkm_wait0() {
  asm volatile("s_waitcnt lgkmcnt(0)" ::: "memory");
  __builtin_amdgcn_sched_barrier(0);
}
__device__ __forceinline__ short8 tr_combine(u32x2 lo, u32x2 hi) {
  u32x4 av; av.x = lo.x; av.y = lo.y; av.z = hi.x; av.w = hi.y;
  return __builtin_bit_cast(short8, av);
}

// wave = expert (8 waves, 512 thr), 64 elems/block, grid 256 = 1 block/CU.
// R18 = R12 structure (4 barriers/stage, best 275 us, no spill) + TR-TRANSPOSE
// (addressing fixed): h/U transpose LDS round-trips store COLUMN-MAJOR
// [u][16 m] u16 via packed ds_write_b64 (MFMA C-layout packs naturally along m
// with pack2_rn — bit-identical rounding to f2b_rn) and read A-frags back with
// ds_read_b64_tr_b16 at addr = tile_base + l15*4 u16. h-writes/wave/stage
// 128 ds_write_b16 -> 32 ds_write_b64; U-writes 16 -> 4. ~40% DS-op cut; the
// dominant bank-conflict source (u16 scatters) is gone. R14-16 post-mortems:
// 2-block co-residency never materializes; wave-local gating needs >128 VGPR
// and the allocator pins 128 (spills ~11.7 MB) — both arms abandoned.
// REGISTER LAW (R5-R13): weights-resident needs VGPR in [100,128]; plain
// __launch_bounds__(512) only.
__global__ __launch_bounds__(512) void ame_ode_kernel(
    const float* __restrict__ x0, const float* __restrict__ tspan,
    const float* __restrict__ W1, const float* __restrict__ b1,
    const float* __restrict__ W2, const float* __restrict__ b2,
    const float* __restrict__ W3, const float* __restrict__ b3,
    const float* __restrict__ Gw1, const float* __restrict__ Gb1,
    const float* __restrict__ Gw2, const float* __restrict__ Gb2,
    float* __restrict__ out)
{
  extern __shared__ __align__(16) u32 dynbuf[];
  u32*  const xdb = dynbuf;                    // [EPB][20] u32: xs bf16x2 (5120 B)
  u32*  const fsb = dynbuf + 1280;             // [EPB][132] u32: f bf16x2, 16B-aligned rows (33792 B)
  float* const lg = (float*)(dynbuf + 9728);   // [EPB][12]: logits (3072 B)
  u16*  const ust16 = (u16*)(dynbuf + 10496);  // U^T [4 mtile][64 u][16 m] u16 (8192 B)
  u32*  const hs  = dynbuf + 12544;            // [8 waves][2 regions][64 u][16 m] u16 (32768 B)

  const int tid  = threadIdx.x;
  const int lane = tid & 63;
  const int l15  = lane & 15;
  const int quad = lane >> 4;
  const int e    = __builtin_amdgcn_readfirstlane(tid >> 6);   // wave-uniform expert id
  const int b    = blockIdx.x * EPB + lane;                    // this lane's batch element

  const float* W1f = W1 + e * (DD + 1) * HH;
  const float* b1f = b1 + e * HH;
  const float* W2f = W2 + e * HH * HH;
  const float* b2f = b2 + e * HH;
  const float* W3f = W3 + e * HH * DD;
  const float* b3f = b3 + e * DD;

  // ---- expert-weight B-frags: B[k=quad*8+j][n=l15(+16nt)] ----
  short8 bw1[4], bw2[2][4], bw3[2][2];
  #pragma unroll
  for (int nt = 0; nt < 4; nt++)
    #pragma unroll
    for (int j = 0; j < 8; j++)
      bw1[nt][j] = (short)f2b_rn(W1f[(quad * 8 + j) * HH + nt * 16 + l15]);
  #pragma unroll
  for (int ks = 0; ks < 2; ks++)
    #pragma unroll
    for (int nt = 0; nt < 4; nt++)
      #pragma unroll
      for (int j = 0; j < 8; j++)
        bw2[ks][nt][j] = (short)f2b_rn(W2f[(ks * 32 + quad * 8 + j) * HH + nt * 16 + l15]);
  #pragma unroll
  for (int ks = 0; ks < 2; ks++)
    #pragma unroll
    for (int dt2 = 0; dt2 < 2; dt2++)
      #pragma unroll
      for (int j = 0; j < 8; j++)
        bw3[ks][dt2][j] = (short)f2b_rn(W3f[(ks * 32 + quad * 8 + j) * DD + dt2 * 16 + l15]);

  // ---- G1: wave e -> M-tile e&3, N-tiles {(e>>2)*2, (e>>2)*2+1}; dx-mean folded ----
  const int g1mt = e & 3;
  const int g1n0 = (e >> 2) * 2;
  short8 bg1x[2], bg1f[2];
  #pragma unroll
  for (int ni = 0; ni < 2; ni++)
    #pragma unroll
    for (int j = 0; j < 8; j++) {
      bg1x[ni][j] = (short)f2b_rn(Gw1[(quad * 8 + j) * HH + (g1n0 + ni) * 16 + l15]);
      bg1f[ni][j] = (short)f2b_rn(0.125f * Gw1[(DD + quad * 8 + j) * HH + (g1n0 + ni) * 16 + l15]);
    }
  const float gb1a = Gb1[g1n0 * 16 + l15];
  const float gb1b = Gb1[(g1n0 + 1) * 16 + l15];

  short8 bg2[2];
  float gb2v = 0.f;
  if (e < 4) {                         // G2: waves 0-3, M-tile = e
    #pragma unroll
    for (int ks = 0; ks < 2; ks++)
      #pragma unroll
      for (int j = 0; j < 8; j++)
        bg2[ks][j] = (short)((l15 < 8) ? f2b_rn(Gw2[(ks * 32 + quad * 8 + j) * EE + l15]) : 0);
    gb2v = (l15 < 8) ? Gb2[l15] : 0.f;
  }

  // per-lane C-init components (col-only), bf16-packed
  u32 c1p[4], c2p[2], c3p;
  #pragma unroll
  for (int nt = 0; nt < 4; nt++)
    c1p[nt] = pack2_rn(b1f[nt * 16 + l15], W1f[DD * HH + nt * 16 + l15]);
  #pragma unroll
  for (int p = 0; p < 2; p++)
    c2p[p] = pack2_rn(b2f[(2 * p) * 16 + l15], b2f[(2 * p + 1) * 16 + l15]);
  c3p = pack2_rn(b3f[l15], b3f[16 + l15]);

  // ---- state init: lane owns dims 4e..4e+3 of elem = lane ----
  float xst[4], xacc[4];
  {
    const float4 v = *(const float4*)(x0 + b * DD + 4 * e);
    xst[0] = v.x; xst[1] = v.y; xst[2] = v.z; xst[3] = v.w;
    xacc[0] = v.x; xacc[1] = v.y; xacc[2] = v.z; xacc[3] = v.w;
    u32x2 p; p.x = pack2_rn(v.x, v.y); p.y = pack2_rn(v.z, v.w);
    *(u32x2*)&xdb[lane * 20 + 2 * e] = p;
    *(float4*)(out + b * TT * DD + 4 * e) = v;
  }
  __syncthreads();

  u16* const fw16 = (u16*)fsb;               // f, row stride 264 u16
  u32* const hsw  = hs + e * 1024;           // this wave's scratch: 2 regions of 512 u32

  #pragma unroll 1
  for (int step = 0; step < TT - 1; step++) {
    const float t0 = tspan[step];
    const float t1 = tspan[step + 1];
    const float dt = t1 - t0;

    #pragma unroll 1
    for (int s = 0; s < 4; s++) {
      const float tcur = (s == 0) ? t0 : ((s == 3) ? t1 : t0 + 0.5f * dt);

      f32x4 c1i[4];
      #pragma unroll
      for (int nt = 0; nt < 4; nt++)
        c1i[nt] = bcast4(__builtin_fmaf(tcur, unp_hi(c1p[nt]), unp_lo(c1p[nt])));

      // ========== Phase A: expert MLP via MFMA (4 M-tiles, ping-pong scratch) ==========
      #pragma unroll 2
      for (int mt = 0; mt < 4; mt++) {
        u16* const hT = (u16*)(hsw + (mt & 1) * 512);   // [64 u][16 m] u16, col-major in m

        const short8 a1 = lds_frag(&xdb[(mt * 16 + l15) * 20 + quad * 4]);
        f32x4 h1a[4];
        #pragma unroll
        for (int nt = 0; nt < 4; nt++)
          h1a[nt] = __builtin_amdgcn_mfma_f32_16x16x32_bf16(a1, bw1[nt], c1i[nt], 0, 0, 0);
        #pragma unroll
        for (int nt = 0; nt < 4; nt++) {
          u32x2 pw;
          pw.x = pack2_rn(fast_tanh(h1a[nt][0]), fast_tanh(h1a[nt][1]));
          pw.y = pack2_rn(fast_tanh(h1a[nt][2]), fast_tanh(h1a[nt][3]));
          *(u32x2*)&hT[(nt * 16 + l15) * 16 + quad * 4] = pw;   // b64, packed along m
        }

        // layer 2: batch-issue 4 tr reads, one drain, then 8 MFMAs
        f32x4 h2a[4];
        #pragma unroll
        for (int nt = 0; nt < 4; nt++)
          h2a[nt] = bcast4((nt & 1) ? unp_hi(c2p[nt >> 1]) : unp_lo(c2p[nt >> 1]));
        {
          const u32x2 t0a = tr_issue(&hT[(0 * 32 + quad * 8) * 16 + l15 * 4]);
          const u32x2 t0b = tr_issue(&hT[(0 * 32 + quad * 8) * 16 + 64 + l15 * 4]);
          const u32x2 t1a = tr_issue(&hT[(1 * 32 + quad * 8) * 16 + l15 * 4]);
          const u32x2 t1b = tr_issue(&hT[(1 * 32 + quad * 8) * 16 + 64 + l15 * 4]);
          lgkm_wait0();
          const short8 a2k0 = tr_combine(t0a, t0b);
          const short8 a2k1 = tr_combine(t1a, t1b);
          #pragma unroll
          for (int nt = 0; nt < 4; nt++)
            h2a[nt] = __builtin_amdgcn_mfma_f32_16x16x32_bf16(a2k0, bw2[0][nt], h2a[nt], 0, 0, 0);
          #pragma unroll
          for (int nt = 0; nt < 4; nt++)
            h2a[nt] = __builtin_amdgcn_mfma_f32_16x16x32_bf16(a2k1, bw2[1][nt], h2a[nt], 0, 0, 0);
        }
        #pragma unroll
        for (int nt = 0; nt < 4; nt++) {
          u32x2 pw;
          pw.x = pack2_rn(fast_tanh(h2a[nt][0]), fast_tanh(h2a[nt][1]));
          pw.y = pack2_rn(fast_tanh(h2a[nt][2]), fast_tanh(h2a[nt][3]));
          *(u32x2*)&hT[(nt * 16 + l15) * 16 + quad * 4] = pw;   // reuse region (in-wave DS order)
        }

        // layer 3: batch-issue 4 tr reads, one drain, then 4 MFMAs
        f32x4 fa[2];
        #pragma unroll
        for (int dt2 = 0; dt2 < 2; dt2++)
          fa[dt2] = bcast4(dt2 ? unp_hi(c3p) : unp_lo(c3p));
        {
          const u32x2 t0a = tr_issue(&hT[(0 * 32 + quad * 8) * 16 + l15 * 4]);
          const u32x2 t0b = tr_issue(&hT[(0 * 32 + quad * 8) * 16 + 64 + l15 * 4]);
          const u32x2 t1a = tr_issue(&hT[(1 * 32 + quad * 8) * 16 + l15 * 4]);
          const u32x2 t1b = tr_issue(&hT[(1 * 32 + quad * 8) * 16 + 64 + l15 * 4]);
          lgkm_wait0();
          const short8 a3k0 = tr_combine(t0a, t0b);
          const short8 a3k1 = tr_combine(t1a, t1b);
          #pragma unroll
          for (int dt2 = 0; dt2 < 2; dt2++)
            fa[dt2] = __builtin_amdgcn_mfma_f32_16x16x32_bf16(a3k0, bw3[0][dt2], fa[dt2], 0, 0, 0);
          #pragma unroll
          for (int dt2 = 0; dt2 < 2; dt2++)
            fa[dt2] = __builtin_amdgcn_mfma_f32_16x16x32_bf16(a3k1, bw3[1][dt2], fa[dt2], 0, 0, 0);
        }
        #pragma unroll
        for (int dt2 = 0; dt2 < 2; dt2++)
          #pragma unroll
          for (int r = 0; r < 4; r++)
            fw16[(mt * 16 + quad * 4 + r) * 264 + e * 32 + dt2 * 16 + l15] = f2b_rn(fa[dt2][r]);
      } // mt
      __syncthreads();   // fs complete

      // ========== G1: U = tanh(x@Gw1x + (Σ_e f_e)@(Gw1dx/8) + Gb1), 2 N-tiles/wave ==========
      {
        f32x4 u0 = bcast4(gb1a), u1 = bcast4(gb1b);
        const int mg = g1mt * 16 + l15;
        const short8 ax = lds_frag(&xdb[mg * 20 + quad * 4]);
        u0 = __builtin_amdgcn_mfma_f32_16x16x32_bf16(ax, bg1x[0], u0, 0, 0, 0);
        u1 = __builtin_amdgcn_mfma_f32_16x16x32_bf16(ax, bg1x[1], u1, 0, 0, 0);
        #pragma unroll
        for (int kb = 0; kb < 8; kb++) {
          const short8 af = lds_frag(&fsb[mg * 132 + kb * 16 + quad * 4]);
          u0 = __builtin_amdgcn_mfma_f32_16x16x32_bf16(af, bg1f[0], u0, 0, 0, 0);
          u1 = __builtin_amdgcn_mfma_f32_16x16x32_bf16(af, bg1f[1], u1, 0, 0, 0);
        }
        // U^T tile writes: [mtile g1mt][u][16 m], packed along m (b64)
        u32x2 p0;
        p0.x = pack2_rn(fast_tanh(u0[0]), fast_tanh(u0[1]));
        p0.y = pack2_rn(fast_tanh(u0[2]), fast_tanh(u0[3]));
        *(u32x2*)&ust16[g1mt * 1024 + (g1n0 * 16 + l15) * 16 + quad * 4] = p0;
        u32x2 p1;
        p1.x = pack2_rn(fast_tanh(u1[0]), fast_tanh(u1[1]));
        p1.y = pack2_rn(fast_tanh(u1[2]), fast_tanh(u1[3]));
        *(u32x2*)&ust16[g1mt * 1024 + ((g1n0 + 1) * 16 + l15) * 16 + quad * 4] = p1;
      }
      __syncthreads();   // U complete

      // ========== G2: logits = U @ Gw2 + Gb2 (waves 0-3, M-tile = e) ==========
      if (e < 4) {
        f32x4 lv = bcast4(gb2v);
        const u32x2 t0a = tr_issue(&ust16[e * 1024 + (0 * 32 + quad * 8) * 16 + l15 * 4]);
        const u32x2 t0b = tr_issue(&ust16[e * 1024 + (0 * 32 + quad * 8) * 16 + 64 + l15 * 4]);
        const u32x2 t1a = tr_issue(&ust16[e * 1024 + (1 * 32 + quad * 8) * 16 + l15 * 4]);
        const u32x2 t1b = tr_issue(&ust16[e * 1024 + (1 * 32 + quad * 8) * 16 + 64 + l15 * 4]);
        lgkm_wait0();
        lv = __builtin_amdgcn_mfma_f32_16x16x32_bf16(tr_combine(t0a, t0b), bg2[0], lv, 0, 0, 0);
        lv = __builtin_amdgcn_mfma_f32_16x16x32_bf16(tr_combine(t1a, t1b), bg2[1], lv, 0, 0, 0);
        if (l15 < 8) {
          #pragma unroll
          for (int r = 0; r < 4; r++)
            lg[(e * 16 + quad * 4 + r) * 12 + l15] = lv[r];
        }
      }
      __syncthreads();   // logits complete

      // ========== C: softmax (no max-sub; logits bounded) + weighted sum + RK4 ==========
      {
        const float4 la0 = *(const float4*)&lg[lane * 12 + 0];
        const float4 la1 = *(const float4*)&lg[lane * 12 + 4];
        float w8[EE];
        w8[0] = __expf(la0.x); w8[1] = __expf(la0.y);
        w8[2] = __expf(la0.z); w8[3] = __expf(la0.w);
        w8[4] = __expf(la1.x); w8[5] = __expf(la1.y);
        w8[6] = __expf(la1.z); w8[7] = __expf(la1.w);
        float ss = 0.f;
        #pragma unroll
        for (int j = 0; j < EE; j++) ss += w8[j];
        const float inv = __builtin_amdgcn_rcpf(ss);

        float kc[4] = {0.f, 0.f, 0.f, 0.f};
        #pragma unroll
        for (int j = 0; j < EE; j++) {
          const float wg = w8[j] * inv;
          const u32x2 p = *(const u32x2*)&fsb[lane * 132 + j * 16 + 2 * e];
          kc[0] = __builtin_fmaf(wg, unp_lo(p.x), kc[0]);
          kc[1] = __builtin_fmaf(wg, unp_hi(p.x), kc[1]);
          kc[2] = __builtin_fmaf(wg, unp_lo(p.y), kc[2]);
          kc[3] = __builtin_fmaf(wg, unp_hi(p.y), kc[3]);
        }

        const float wk = (s == 1 || s == 2) ? 2.f : 1.f;
        const float ak = dt * (1.f / 6.f) * wk;
        #pragma unroll
        for (int q = 0; q < 4; q++) xacc[q] = __builtin_fmaf(ak, kc[q], xacc[q]);

        float xn[4];
        if (s < 3) {
          const float cn = (s == 2) ? dt : 0.5f * dt;
          #pragma unroll
          for (int q = 0; q < 4; q++) xn[q] = __builtin_fmaf(cn, kc[q], xst[q]);
        } else {
          #pragma unroll
          for (int q = 0; q < 4; q++) { xst[q] = xacc[q]; xn[q] = xacc[q]; }
          float4 o; o.x = xn[0]; o.y = xn[1]; o.z = xn[2]; o.w = xn[3];
          *(float4*)(out + (b * TT + step + 1) * DD + 4 * e) = o;
        }
        u32x2 p; p.x = pack2_rn(xn[0], xn[1]); p.y = pack2_rn(xn[2], xn[3]);
        *(u32x2*)&xdb[lane * 20 + 2 * e] = p;
      }
      __syncthreads();   // end of stage
    } // stages
  } // steps
}

extern "C" void kernel_launch(void* const* d_in, const int* in_sizes, int n_in,
                              void* d_out, int out_size, void* d_ws, size_t ws_size,
                              hipStream_t stream)
{
  const float* x0    = (const float*)d_in[0];
  const float* tspan = (const float*)d_in[1];
  const float* W1  = (const float*)d_in[2];
  const float* b1  = (const float*)d_in[3];
  const float* W2  = (const float*)d_in[4];
  const float* b2  = (const float*)d_in[5];
  const float* W3  = (const float*)d_in[6];
  const float* b3  = (const float*)d_in[7];
  const float* Gw1 = (const float*)d_in[8];
  const float* Gb1 = (const float*)d_in[9];
  const float* Gw2 = (const float*)d_in[10];
  const float* Gb2 = (const float*)d_in[11];

  // Opt in to >64 KB dynamic LDS (160 KB/CU on gfx950). Host-side, idempotent,
  // graph-capture safe. Called unconditionally every launch.
  (void)hipFuncSetAttribute((const void*)ame_ode_kernel,
                            hipFuncAttributeMaxDynamicSharedMemorySize, DYN_LDS);

  ame_ode_kernel<<<BATCH / EPB, 512, DYN_LDS, stream>>>(
      x0, tspan, W1, b1, W2, b2, W3, b3, Gw1, Gb1, Gw2, Gb2, (float*)d_out);
}

// Round 6
// 334.404 us; speedup vs baseline: 1.0520x; 1.0039x over previous
//
#include <hip/hip_runtime.h>
#include <hip/hip_bf16.h>

typedef unsigned int u32;
typedef unsigned short u16;
typedef __attribute__((ext_vector_type(8))) short short8;   // 8 bf16 (4 VGPRs) MFMA A/B frag
typedef __attribute__((ext_vector_type(4))) float f32x4;    // MFMA C/D frag
typedef __attribute__((ext_vector_type(4))) u32 u32x4;
typedef __attribute__((ext_vector_type(2))) u32 u32x2;

#define DD 32
#define EE 8
#define HH 64
#define TT 10
#define BATCH 16384
#define EPB 64          // batch elements per block (grid 256 = 1 block/CU)
#define DYN_LDS 91968   // bytes; layout documented at dynbuf below

#if __has_builtin(__builtin_amdgcn_exp2f)
#define EXP2F(x) __builtin_amdgcn_exp2f(x)
#else
#define EXP2F(x) __builtin_exp2f(x)
#endif

__device__ __forceinline__ float fast_tanh(float x) {
  float e = EXP2F(x * 2.885390082f);
  return 1.f - 2.f * __builtin_amdgcn_rcpf(e + 1.f);
}
__device__ __forceinline__ u16 f2b_rn(float v) {
  return (u16)((__float_as_uint(v) + 0x8000u) >> 16);
}
__device__ __forceinline__ u32 pack2_rn(float a, float b) {   // lo u16 = bf16(a), hi = bf16(b)
  return __builtin_amdgcn_perm(__float_as_uint(b) + 0x8000u,
                               __float_as_uint(a) + 0x8000u, 0x07060302u);
}
__device__ __forceinline__ float unp_lo(u32 p) { return __uint_as_float(p << 16); }
__device__ __forceinline__ float unp_hi(u32 p) { return __uint_as_float(p & 0xffff0000u); }
__device__ __forceinline__ short8 lds_frag(const u32* p) {
  u32x4 v = *(const u32x4*)p;               // ds_read_b128 (16B-aligned by construction)
  return __builtin_bit_cast(short8, v);
}

// wave = expert (8 waves, 512 thr), 64 elems/block, grid 256 = 1 block/CU.
// R19 = TRANSPOSED COMPUTE. R18 post-mortem: tr-reads are 4-way-conflicted by
// construction (m217) — conflicts 1.15e7 -> 4.16e7, dur 289. Fix at the root:
// make batch the MFMA N dim everywhere by SWAPPING OPERANDS:
//   mfma(W_frags, act_frags, C)  computes  (act @ W)^T
// Identities: A-frag of W^T == B-frag of W (same registers, unchanged loads);
// B-frag of x^T from row-major [m][d] == A-frag of x (same LDS reads).
// Output C-layout: col l15 = batch elem, rows quad*4+r = 4 CONSECUTIVE
// features of one row -> all intermediate stores become packed ds_write_b64
// (h 16 scatters->4 b64/layer, f 8->2, U 16->2, logits 4xb32->1 b128); all
// reads stay contiguous ds_read_b128. No tr reads, no scatters. DS instr
// ~185 -> ~116 /stage/wave. C-init biases now vary along rows (4 vals/lane):
// kept in tiny per-expert LDS tables (quad-uniform broadcast reads, free) to
// AVOID the R15/R16 spill trap — net -10 VGPR vs R12. Same math per output
// element (same k-order, same bf16 roundings). 4 barriers/stage as R12.
// REGISTER LAW (R5-R16): VGPR must stay <=128; plain __launch_bounds__(512).
__global__ __launch_bounds__(512) void ame_ode_kernel(
    const float* __restrict__ x0, const float* __restrict__ tspan,
    const float* __restrict__ W1, const float* __restrict__ b1,
    const float* __restrict__ W2, const float* __restrict__ b2,
    const float* __restrict__ W3, const float* __restrict__ b3,
    const float* __restrict__ Gw1, const float* __restrict__ Gb1,
    const float* __restrict__ Gw2, const float* __restrict__ Gb2,
    float* __restrict__ out)
{
  extern __shared__ __align__(16) u32 dynbuf[];
  // u32 offsets:
  u32*  const xdb  = dynbuf;                  // [64][20] u32: xs bf16x2          (5120 B)
  u32*  const fsb  = dynbuf + 1280;           // [64][132] u32: f bf16x2 rows     (33792 B)
  float* const lg  = (float*)(dynbuf + 9728); // [64][12] f32: logits             (3072 B)
  u32*  const ust  = dynbuf + 10496;          // U [64 m][72 u16] rows            (9216 B)
  u32*  const hs   = dynbuf + 12800;          // [8 waves][2 regions][16 m][72 u16] (36864 B)
  u32*  const cb1  = dynbuf + 22016;          // [8][64] u32 pack(b1[g], W1t[g])  (2048 B)
  u32*  const cb2  = dynbuf + 22528;          // [8][32] u32 pack(b2 pairs)       (1024 B)
  u32*  const cb3  = dynbuf + 22784;          // [8][16] u32 pack(b3 pairs)       (512 B)
  float* const gb1s = (float*)(dynbuf + 22912); // [64] f32 Gb1                   (256 B)
  float* const gb2s = (float*)(dynbuf + 22976); // [16] f32 Gb2 (8 valid + pad)   (64 B)

  const int tid  = threadIdx.x;
  const int lane = tid & 63;
  const int l15  = lane & 15;
  const int quad = lane >> 4;
  const int e    = __builtin_amdgcn_readfirstlane(tid >> 6);   // wave-uniform expert id
  const int b    = blockIdx.x * EPB + lane;                    // this lane's batch element

  const float* W1f = W1 + e * (DD + 1) * HH;
  const float* b1f = b1 + e * HH;
  const float* W2f = W2 + e * HH * HH;
  const float* b2f = b2 + e * HH;
  const float* W3f = W3 + e * HH * DD;
  const float* b3f = b3 + e * DD;

  // ---- expert-weight frags (identical registers to R12; now passed as the A
  //      operand: A-frag of W^T == B-frag of W) ----
  short8 bw1[4], bw2[2][4], bw3[2][2];
  #pragma unroll
  for (int nt = 0; nt < 4; nt++)
    #pragma unroll
    for (int j = 0; j < 8; j++)
      bw1[nt][j] = (short)f2b_rn(W1f[(quad * 8 + j) * HH + nt * 16 + l15]);
  #pragma unroll
  for (int ks = 0; ks < 2; ks++)
    #pragma unroll
    for (int nt = 0; nt < 4; nt++)
      #pragma unroll
      for (int j = 0; j < 8; j++)
        bw2[ks][nt][j] = (short)f2b_rn(W2f[(ks * 32 + quad * 8 + j) * HH + nt * 16 + l15]);
  #pragma unroll
  for (int ks = 0; ks < 2; ks++)
    #pragma unroll
    for (int dt2 = 0; dt2 < 2; dt2++)
      #pragma unroll
      for (int j = 0; j < 8; j++)
        bw3[ks][dt2][j] = (short)f2b_rn(W3f[(ks * 32 + quad * 8 + j) * DD + dt2 * 16 + l15]);

  // ---- G1: wave e -> batch N-tile e&3, u M-tiles {(e>>2)*2, +1}; 1/8 folded ----
  const int g1mt = e & 3;          // batch tile (N)
  const int g1n0 = (e >> 2) * 2;   // u tile base (M)
  short8 bg1x[2], bg1f[2];
  #pragma unroll
  for (int ni = 0; ni < 2; ni++)
    #pragma unroll
    for (int j = 0; j < 8; j++) {
      bg1x[ni][j] = (short)f2b_rn(Gw1[(quad * 8 + j) * HH + (g1n0 + ni) * 16 + l15]);
      bg1f[ni][j] = (short)f2b_rn(0.125f * Gw1[(DD + quad * 8 + j) * HH + (g1n0 + ni) * 16 + l15]);
    }

  short8 bg2[2];
  if (e < 4) {                     // G2: waves 0-3, batch N-tile = e
    #pragma unroll
    for (int ks = 0; ks < 2; ks++)
      #pragma unroll
      for (int j = 0; j < 8; j++)
        bg2[ks][j] = (short)((l15 < 8) ? f2b_rn(Gw2[(ks * 32 + quad * 8 + j) * EE + l15]) : 0);
  }

  // ---- C-init constant tables -> LDS (per-expert; quad-uniform broadcast reads) ----
  {
    u32* const c1e = cb1 + e * 64;
    c1e[lane] = pack2_rn(b1f[lane], W1f[DD * HH + lane]);
    if (lane < 32) (cb2 + e * 32)[lane] = pack2_rn(b2f[2 * lane], b2f[2 * lane + 1]);
    if (lane < 16) (cb3 + e * 16)[lane] = pack2_rn(b3f[2 * lane], b3f[2 * lane + 1]);
    if (e == 0) {
      gb1s[lane] = Gb1[lane];
      if (lane < 16) gb2s[lane] = (lane < 8) ? Gb2[lane] : 0.f;
    }
  }

  // ---- state init: lane owns dims 4e..4e+3 of elem = lane ----
  float xst[4], xacc[4];
  {
    const float4 v = *(const float4*)(x0 + b * DD + 4 * e);
    xst[0] = v.x; xst[1] = v.y; xst[2] = v.z; xst[3] = v.w;
    xacc[0] = v.x; xacc[1] = v.y; xacc[2] = v.z; xacc[3] = v.w;
    u32x2 p; p.x = pack2_rn(v.x, v.y); p.y = pack2_rn(v.z, v.w);
    *(u32x2*)&xdb[lane * 20 + 2 * e] = p;
    *(float4*)(out + b * TT * DD + 4 * e) = v;
  }
  __syncthreads();

  u16* const fw16  = (u16*)fsb;              // f, row stride 264 u16
  u32* const hsw   = hs + e * 1152;          // this wave's scratch: 2 regions of 576 u32
  u16* const ust16 = (u16*)ust;
  const u32* const c1e = cb1 + e * 64;
  const u32* const c2e = cb2 + e * 32;
  const u32* const c3e = cb3 + e * 16;

  #pragma unroll 1
  for (int step = 0; step < TT - 1; step++) {
    const float t0 = tspan[step];
    const float t1 = tspan[step + 1];
    const float dt = t1 - t0;

    #pragma unroll 1
    for (int s = 0; s < 4; s++) {
      const float tcur = (s == 0) ? t0 : ((s == 3) ? t1 : t0 + 0.5f * dt);

      // layer-1 C-init: rows g = nt*16+quad*4+r (4 distinct values/lane)
      f32x4 c1i[4];
      #pragma unroll
      for (int nt = 0; nt < 4; nt++) {
        const u32x4 cw = *(const u32x4*)&c1e[nt * 16 + quad * 4];   // broadcast b128
        c1i[nt][0] = __builtin_fmaf(tcur, unp_hi(cw[0]), unp_lo(cw[0]));
        c1i[nt][1] = __builtin_fmaf(tcur, unp_hi(cw[1]), unp_lo(cw[1]));
        c1i[nt][2] = __builtin_fmaf(tcur, unp_hi(cw[2]), unp_lo(cw[2]));
        c1i[nt][3] = __builtin_fmaf(tcur, unp_hi(cw[3]), unp_lo(cw[3]));
      }

      // ========== Phase A: expert MLP, transposed (4 batch N-tiles, ping-pong) ==========
      #pragma unroll 2
      for (int mt = 0; mt < 4; mt++) {
        u32* const hT32 = hsw + (mt & 1) * 576;     // h row-major [16 m][72 u16]
        u16* const hT16 = (u16*)hT32;

        // B = x^T from xdb rows (identical read to R12's A-frag)
        const short8 a1 = lds_frag(&xdb[(mt * 16 + l15) * 20 + quad * 4]);
        f32x4 h1a[4];
        #pragma unroll
        for (int nt = 0; nt < 4; nt++)
          h1a[nt] = __builtin_amdgcn_mfma_f32_16x16x32_bf16(bw1[nt], a1, c1i[nt], 0, 0, 0);
        #pragma unroll
        for (int nt = 0; nt < 4; nt++) {            // packed b64: row l15, cols nt*16+quad*4..+3
          u32x2 pw;
          pw.x = pack2_rn(fast_tanh(h1a[nt][0]), fast_tanh(h1a[nt][1]));
          pw.y = pack2_rn(fast_tanh(h1a[nt][2]), fast_tanh(h1a[nt][3]));
          *(u32x2*)&hT16[l15 * 72 + nt * 16 + quad * 4] = pw;
        }

        // layer 2
        f32x4 h2a[4];
        #pragma unroll
        for (int nt = 0; nt < 4; nt++) {
          const u32x2 cw = *(const u32x2*)&c2e[nt * 8 + quad * 2];  // broadcast b64
          h2a[nt][0] = unp_lo(cw.x); h2a[nt][1] = unp_hi(cw.x);
          h2a[nt][2] = unp_lo(cw.y); h2a[nt][3] = unp_hi(cw.y);
        }
        const short8 a2k0 = lds_frag(&hT32[l15 * 36 + quad * 4]);
        const short8 a2k1 = lds_frag(&hT32[l15 * 36 + 16 + quad * 4]);
        #pragma unroll
        for (int nt = 0; nt < 4; nt++)
          h2a[nt] = __builtin_amdgcn_mfma_f32_16x16x32_bf16(bw2[0][nt], a2k0, h2a[nt], 0, 0, 0);
        #pragma unroll
        for (int nt = 0; nt < 4; nt++)
          h2a[nt] = __builtin_amdgcn_mfma_f32_16x16x32_bf16(bw2[1][nt], a2k1, h2a[nt], 0, 0, 0);
        #pragma unroll
        for (int nt = 0; nt < 4; nt++) {
          u32x2 pw;
          pw.x = pack2_rn(fast_tanh(h2a[nt][0]), fast_tanh(h2a[nt][1]));
          pw.y = pack2_rn(fast_tanh(h2a[nt][2]), fast_tanh(h2a[nt][3]));
          *(u32x2*)&hT16[l15 * 72 + nt * 16 + quad * 4] = pw;      // reuse region (in-wave order)
        }

        // layer 3
        f32x4 fa[2];
        #pragma unroll
        for (int dt2 = 0; dt2 < 2; dt2++) {
          const u32x2 cw = *(const u32x2*)&c3e[dt2 * 8 + quad * 2];
          fa[dt2][0] = unp_lo(cw.x); fa[dt2][1] = unp_hi(cw.x);
          fa[dt2][2] = unp_lo(cw.y); fa[dt2][3] = unp_hi(cw.y);
        }
        const short8 a3k0 = lds_frag(&hT32[l15 * 36 + quad * 4]);
        const short8 a3k1 = lds_frag(&hT32[l15 * 36 + 16 + quad * 4]);
        #pragma unroll
        for (int dt2 = 0; dt2 < 2; dt2++)
          fa[dt2] = __builtin_amdgcn_mfma_f32_16x16x32_bf16(bw3[0][dt2], a3k0, fa[dt2], 0, 0, 0);
        #pragma unroll
        for (int dt2 = 0; dt2 < 2; dt2++)
          fa[dt2] = __builtin_amdgcn_mfma_f32_16x16x32_bf16(bw3[1][dt2], a3k1, fa[dt2], 0, 0, 0);
        // f store: packed b64, row (mt*16+l15), cols e*32 + dt2*16 + quad*4..+3
        #pragma unroll
        for (int dt2 = 0; dt2 < 2; dt2++) {
          u32x2 pw;
          pw.x = pack2_rn(fa[dt2][0], fa[dt2][1]);
          pw.y = pack2_rn(fa[dt2][2], fa[dt2][3]);
          *(u32x2*)&fw16[(mt * 16 + l15) * 264 + e * 32 + dt2 * 16 + quad * 4] = pw;
        }
      } // mt
      __syncthreads();   // fs complete

      // ========== G1 (transposed): U^T = Gw1^T @ [x;f]^T; wave: N=batch tile g1mt,
      //            M = u tiles g1n0, g1n0+1 (B-frags shared across both M-tiles) ==========
      {
        f32x4 ug[2];
        #pragma unroll
        for (int mi = 0; mi < 2; mi++) {
          const float4 gbv = *(const float4*)&gb1s[(g1n0 + mi) * 16 + quad * 4];  // broadcast
          ug[mi][0] = gbv.x; ug[mi][1] = gbv.y; ug[mi][2] = gbv.z; ug[mi][3] = gbv.w;
        }
        const int mg = g1mt * 16 + l15;
        const short8 bx = lds_frag(&xdb[mg * 20 + quad * 4]);
        ug[0] = __builtin_amdgcn_mfma_f32_16x16x32_bf16(bg1x[0], bx, ug[0], 0, 0, 0);
        ug[1] = __builtin_amdgcn_mfma_f32_16x16x32_bf16(bg1x[1], bx, ug[1], 0, 0, 0);
        #pragma unroll
        for (int kb = 0; kb < 8; kb++) {
          const short8 bf = lds_frag(&fsb[mg * 132 + kb * 16 + quad * 4]);
          ug[0] = __builtin_amdgcn_mfma_f32_16x16x32_bf16(bg1f[0], bf, ug[0], 0, 0, 0);
          ug[1] = __builtin_amdgcn_mfma_f32_16x16x32_bf16(bg1f[1], bf, ug[1], 0, 0, 0);
        }
        // U store: packed b64, row m=mg, cols (g1n0+mi)*16+quad*4..+3
        #pragma unroll
        for (int mi = 0; mi < 2; mi++) {
          u32x2 pw;
          pw.x = pack2_rn(fast_tanh(ug[mi][0]), fast_tanh(ug[mi][1]));
          pw.y = pack2_rn(fast_tanh(ug[mi][2]), fast_tanh(ug[mi][3]));
          *(u32x2*)&ust16[mg * 72 + (g1n0 + mi) * 16 + quad * 4] = pw;
        }
      }
      __syncthreads();   // U complete

      // ========== G2 (transposed): logits^T = Gw2^T @ U^T (waves 0-3, N-tile = e) ==========
      if (e < 4) {
        const float4 g2b = *(const float4*)&gb2s[quad * 4];   // quads 2,3 read zero pad
        f32x4 lv; lv[0] = g2b.x; lv[1] = g2b.y; lv[2] = g2b.z; lv[3] = g2b.w;
        const short8 bu0 = lds_frag(&ust[(e * 16 + l15) * 36 + quad * 4]);
        const short8 bu1 = lds_frag(&ust[(e * 16 + l15) * 36 + 16 + quad * 4]);
        lv = __builtin_amdgcn_mfma_f32_16x16x32_bf16(bg2[0], bu0, lv, 0, 0, 0);
        lv = __builtin_amdgcn_mfma_f32_16x16x32_bf16(bg2[1], bu1, lv, 0, 0, 0);
        if (quad < 2) {              // rows quad*4+r = experts 0..7; one b128 store
          float4 o; o.x = lv[0]; o.y = lv[1]; o.z = lv[2]; o.w = lv[3];
          *(float4*)&lg[(e * 16 + l15) * 12 + quad * 4] = o;
        }
      }
      __syncthreads();   // logits complete

      // ========== C: softmax (no max-sub; logits bounded) + weighted sum + RK4 ==========
      {
        const float4 la0 = *(const float4*)&lg[lane * 12 + 0];
        const float4 la1 = *(const float4*)&lg[lane * 12 + 4];
        float w8[EE];
        w8[0] = __expf(la0.x); w8[1] = __expf(la0.y);
        w8[2] = __expf(la0.z); w8[3] = __expf(la0.w);
        w8[4] = __expf(la1.x); w8[5] = __expf(la1.y);
        w8[6] = __expf(la1.z); w8[7] = __expf(la1.w);
        float ss = 0.f;
        #pragma unroll
        for (int j = 0; j < EE; j++) ss += w8[j];
        const float inv = __builtin_amdgcn_rcpf(ss);

        float kc[4] = {0.f, 0.f, 0.f, 0.f};
        #pragma unroll
        for (int j = 0; j < EE; j++) {
          const float wg = w8[j] * inv;
          const u32x2 p = *(const u32x2*)&fsb[lane * 132 + j * 16 + 2 * e];
          kc[0] = __builtin_fmaf(wg, unp_lo(p.x), kc[0]);
          kc[1] = __builtin_fmaf(wg, unp_hi(p.x), kc[1]);
          kc[2] = __builtin_fmaf(wg, unp_lo(p.y), kc[2]);
          kc[3] = __builtin_fmaf(wg, unp_hi(p.y), kc[3]);
        }

        const float wk = (s == 1 || s == 2) ? 2.f : 1.f;
        const float ak = dt * (1.f / 6.f) * wk;
        #pragma unroll
        for (int q = 0; q < 4; q++) xacc[q] = __builtin_fmaf(ak, kc[q], xacc[q]);

        float xn[4];
        if (s < 3) {
          const float cn = (s == 2) ? dt : 0.5f * dt;
          #pragma unroll
          for (int q = 0; q < 4; q++) xn[q] = __builtin_fmaf(cn, kc[q], xst[q]);
        } else {
          #pragma unroll
          for (int q = 0; q < 4; q++) { xst[q] = xacc[q]; xn[q] = xacc[q]; }
          float4 o; o.x = xn[0]; o.y = xn[1]; o.z = xn[2]; o.w = xn[3];
          *(float4*)(out + (b * TT + step + 1) * DD + 4 * e) = o;
        }
        u32x2 p; p.x = pack2_rn(xn[0], xn[1]); p.y = pack2_rn(xn[2], xn[3]);
        *(u32x2*)&xdb[lane * 20 + 2 * e] = p;
      }
      __syncthreads();   // end of stage
    } // stages
  } // steps
}

extern "C" void kernel_launch(void* const* d_in, const int* in_sizes, int n_in,
                              void* d_out, int out_size, void* d_ws, size_t ws_size,
                              hipStream_t stream)
{
  const float* x0    = (const float*)d_in[0];
  const float* tspan = (const float*)d_in[1];
  const float* W1  = (const float*)d_in[2];
  const float* b1  = (const float*)d_in[3];
  const float* W2  = (const float*)d_in[4];
  const float* b2  = (const float*)d_in[5];
  const float* W3  = (const float*)d_in[6];
  const float* b3  = (const float*)d_in[7];
  const float* Gw1 = (const float*)d_in[8];
  const float* Gb1 = (const float*)d_in[9];
  const float* Gw2 = (const float*)d_in[10];
  const float* Gb2 = (const float*)d_in[11];

  // Opt in to >64 KB dynamic LDS (160 KB/CU on gfx950). Host-side, idempotent,
  // graph-capture safe. Called unconditionally every launch.
  (void)hipFuncSetAttribute((const void*)ame_ode_kernel,
                            hipFuncAttributeMaxDynamicSharedMemorySize, DYN_LDS);

  ame_ode_kernel<<<BATCH / EPB, 512, DYN_LDS, stream>>>(
      x0, tspan, W1, b1, W2, b2, W3, b3, Gw1, Gb1, Gw2, Gb2, (float*)d_out);
}

// Round 7
// 331.977 us; speedup vs baseline: 1.0597x; 1.0073x over previous
//
#include <hip/hip_runtime.h>
#include <hip/hip_bf16.h>

typedef unsigned int u32;
typedef unsigned short u16;
typedef __attribute__((ext_vector_type(8))) short short8;   // 8 bf16 (4 VGPRs) MFMA A/B frag
typedef __attribute__((ext_vector_type(4))) float f32x4;    // MFMA C/D frag
typedef __attribute__((ext_vector_type(4))) u32 u32x4;
typedef __attribute__((ext_vector_type(2))) u32 u32x2;

#define DD 32
#define EE 8
#define HH 64
#define TT 10
#define BATCH 16384
#define EPB 64          // batch elements per block (grid 256 = 1 block/CU)
#define DYN_LDS 84992   // bytes: xdb 5120 + fsb 33792 + usb 9216 + hs 36864

#if __has_builtin(__builtin_amdgcn_exp2f)
#define EXP2F(x) __builtin_amdgcn_exp2f(x)
#else
#define EXP2F(x) __builtin_exp2f(x)
#endif

__device__ __forceinline__ float fast_tanh(float x) {
  float e = EXP2F(x * 2.885390082f);
  return 1.f - 2.f * __builtin_amdgcn_rcpf(e + 1.f);
}
__device__ __forceinline__ u16 f2b_rn(float v) {
  return (u16)((__float_as_uint(v) + 0x8000u) >> 16);
}
__device__ __forceinline__ u32 pack2_rn(float a, float b) {
  return __builtin_amdgcn_perm(__float_as_uint(b) + 0x8000u,
                               __float_as_uint(a) + 0x8000u, 0x07060302u);
}
__device__ __forceinline__ float unp_lo(u32 p) { return __uint_as_float(p << 16); }
__device__ __forceinline__ float unp_hi(u32 p) { return __uint_as_float(p & 0xffff0000u); }
__device__ __forceinline__ short8 lds_frag(const u32* p) {
  u32x4 v = *(const u32x4*)p;               // ds_read_b128 (16B-aligned by construction)
  return __builtin_bit_cast(short8, v);
}
__device__ __forceinline__ f32x4 bcast4(float v) { f32x4 c; c[0]=v; c[1]=v; c[2]=v; c[3]=v; return c; }

// wave = expert (8 waves, 512 thr), 64 elems/block, grid 256 = 1 block/CU.
// R20 = R12 (best: 275 us, layouts byte-identical) with BARRIERS 4 -> 3:
// G2 + softmax + weighted-sum + RK4 are merged into one WAVE-LOCAL phase.
// Evidence trail: R13 (fsb swizzle), R18 (tr-reads, conflicts 1.15e7->4.16e7)
// and R19 (transposed compute, ->2.39e7) all proved R12's scatter layout is
// the conflict-landscape optimum — DO NOT touch phase-A/G1 LDS patterns.
// R15 proved wave-local gating works but replicating G1 weights blew the
// 128-VGPR cap (spill). G2-only replication is FREE: bg2/gb2v are uniformly
// allocated in all waves already (the old if(e<4) didn't shrink allocation).
// Each wave computes logits for its own 8 elems (A-rows = elems 8e..8e+7
// dup'd x2), softmax over expert lanes via shfl_xor (DPP/VALU, zero DS),
// weight exchange via per-wave hs scratch (in-wave DS order, R15-proven),
// then kc/RK4 with el/q8 mapping. Deletes: G2->C barrier, lg buffer (its
// 4-way-conflicted store + 2 reads/lane), the 4-idle-wave G2 bubble.
// REGISTER LAW (R5-R19): VGPR must stay <= 128 (cap is hard; excess spills
// ~MBs to scratch). This edit is ~-4 VGPR vs R12. Plain __launch_bounds__(512).
__global__ __launch_bounds__(512) void ame_ode_kernel(
    const float* __restrict__ x0, const float* __restrict__ tspan,
    const float* __restrict__ W1, const float* __restrict__ b1,
    const float* __restrict__ W2, const float* __restrict__ b2,
    const float* __restrict__ W3, const float* __restrict__ b3,
    const float* __restrict__ Gw1, const float* __restrict__ Gb1,
    const float* __restrict__ Gw2, const float* __restrict__ Gb2,
    float* __restrict__ out)
{
  extern __shared__ __align__(16) u32 dynbuf[];
  u32*  const xdb = dynbuf;                    // [EPB][20] u32: xs bf16x2 (5120 B)
  u32*  const fsb = dynbuf + 1280;             // [EPB][132] u32: f bf16x2, 16B-aligned rows (33792 B)
  u32*  const usb = dynbuf + 9728;             // [EPB][36] u32: gating U (9216 B)
  u32*  const hs  = dynbuf + 12032;            // [8 waves][2 regions][16][36] u32 scratch (36864 B)

  const int tid  = threadIdx.x;
  const int lane = tid & 63;
  const int l15  = lane & 15;
  const int quad = lane >> 4;
  const int e    = __builtin_amdgcn_readfirstlane(tid >> 6);   // wave-uniform expert id

  // wave-local gating/C mapping: wave e owns elems 8e..8e+7
  const int el = lane >> 3;                    // element within wave's 8
  const int q8 = lane & 7;                     // dim-quad index (dims 4*q8..4*q8+3)
  const int gr = e * 8 + el;                   // block-local gated row
  const int gb = blockIdx.x * EPB + gr;        // global batch element

  const float* W1f = W1 + e * (DD + 1) * HH;
  const float* b1f = b1 + e * HH;
  const float* W2f = W2 + e * HH * HH;
  const float* b2f = b2 + e * HH;
  const float* W3f = W3 + e * HH * DD;
  const float* b3f = b3 + e * DD;

  // ---- expert-weight B-frags: B[k=quad*8+j][n=l15(+16nt)] ----
  short8 bw1[4], bw2[2][4], bw3[2][2];
  #pragma unroll
  for (int nt = 0; nt < 4; nt++)
    #pragma unroll
    for (int j = 0; j < 8; j++)
      bw1[nt][j] = (short)f2b_rn(W1f[(quad * 8 + j) * HH + nt * 16 + l15]);
  #pragma unroll
  for (int ks = 0; ks < 2; ks++)
    #pragma unroll
    for (int nt = 0; nt < 4; nt++)
      #pragma unroll
      for (int j = 0; j < 8; j++)
        bw2[ks][nt][j] = (short)f2b_rn(W2f[(ks * 32 + quad * 8 + j) * HH + nt * 16 + l15]);
  #pragma unroll
  for (int ks = 0; ks < 2; ks++)
    #pragma unroll
    for (int dt2 = 0; dt2 < 2; dt2++)
      #pragma unroll
      for (int j = 0; j < 8; j++)
        bw3[ks][dt2][j] = (short)f2b_rn(W3f[(ks * 32 + quad * 8 + j) * DD + dt2 * 16 + l15]);

  // ---- G1: wave e -> M-tile e&3, N-tiles {(e>>2)*2, (e>>2)*2+1}; dx-mean folded ----
  const int g1mt = e & 3;
  const int g1n0 = (e >> 2) * 2;
  short8 bg1x[2], bg1f[2];
  #pragma unroll
  for (int ni = 0; ni < 2; ni++)
    #pragma unroll
    for (int j = 0; j < 8; j++) {
      bg1x[ni][j] = (short)f2b_rn(Gw1[(quad * 8 + j) * HH + (g1n0 + ni) * 16 + l15]);
      bg1f[ni][j] = (short)f2b_rn(0.125f * Gw1[(DD + quad * 8 + j) * HH + (g1n0 + ni) * 16 + l15]);
    }
  const float gb1a = Gb1[g1n0 * 16 + l15];
  const float gb1b = Gb1[(g1n0 + 1) * 16 + l15];

  // ---- G2 weights: ALL waves (uniform allocation anyway; enables wave-local G2) ----
  short8 bg2[2];
  #pragma unroll
  for (int ks = 0; ks < 2; ks++)
    #pragma unroll
    for (int j = 0; j < 8; j++)
      bg2[ks][j] = (short)((l15 < 8) ? f2b_rn(Gw2[(ks * 32 + quad * 8 + j) * EE + l15]) : 0);
  const float gb2v = (l15 < 8) ? Gb2[l15] : 0.f;

  // per-lane C-init components (col-only), bf16-packed
  u32 c1p[4], c2p[2], c3p;
  #pragma unroll
  for (int nt = 0; nt < 4; nt++)
    c1p[nt] = pack2_rn(b1f[nt * 16 + l15], W1f[DD * HH + nt * 16 + l15]);
  #pragma unroll
  for (int p = 0; p < 2; p++)
    c2p[p] = pack2_rn(b2f[(2 * p) * 16 + l15], b2f[(2 * p + 1) * 16 + l15]);
  c3p = pack2_rn(b3f[l15], b3f[16 + l15]);

  // ---- state init: lane owns dims 4*q8..4*q8+3 of elem gr ----
  float xst[4], xacc[4];
  {
    const float4 v = *(const float4*)(x0 + gb * DD + 4 * q8);
    xst[0] = v.x; xst[1] = v.y; xst[2] = v.z; xst[3] = v.w;
    xacc[0] = v.x; xacc[1] = v.y; xacc[2] = v.z; xacc[3] = v.w;
    u32x2 p; p.x = pack2_rn(v.x, v.y); p.y = pack2_rn(v.z, v.w);
    *(u32x2*)&xdb[gr * 20 + q8 * 2] = p;
    *(float4*)(out + gb * TT * DD + 4 * q8) = v;
  }
  __syncthreads();

  u16* const fw16 = (u16*)fsb;               // f, row stride 264 u16
  u16* const us16 = (u16*)usb;               // U, row stride 72 u16
  u32* const hsw  = hs + e * 1152;           // this wave's scratch (2 regions of 576 u32)

  #pragma unroll 1
  for (int step = 0; step < TT - 1; step++) {
    const float t0 = tspan[step];
    const float t1 = tspan[step + 1];
    const float dt = t1 - t0;

    #pragma unroll 1
    for (int s = 0; s < 4; s++) {
      const float tcur = (s == 0) ? t0 : ((s == 3) ? t1 : t0 + 0.5f * dt);

      f32x4 c1i[4];
      #pragma unroll
      for (int nt = 0; nt < 4; nt++)
        c1i[nt] = bcast4(__builtin_fmaf(tcur, unp_hi(c1p[nt]), unp_lo(c1p[nt])));

      // ========== Phase A: expert MLP via MFMA (4 M-tiles, ping-pong scratch) ==========
      // Byte-identical to R12 (layout = measured conflict optimum).
      #pragma unroll 2
      for (int mt = 0; mt < 4; mt++) {
        u32* const hw   = hsw + (mt & 1) * 576;   // disjoint region per mt parity
        u16* const hw16 = (u16*)hw;

        const short8 a1 = lds_frag(&xdb[(mt * 16 + l15) * 20 + quad * 4]);
        f32x4 h1a[4];
        #pragma unroll
        for (int nt = 0; nt < 4; nt++)
          h1a[nt] = __builtin_amdgcn_mfma_f32_16x16x32_bf16(a1, bw1[nt], c1i[nt], 0, 0, 0);
        #pragma unroll
        for (int nt = 0; nt < 4; nt++)
          #pragma unroll
          for (int r = 0; r < 4; r++)
            hw16[(quad * 4 + r) * 72 + nt * 16 + l15] = f2b_rn(fast_tanh(h1a[nt][r]));

        f32x4 h2a[4];
        #pragma unroll
        for (int nt = 0; nt < 4; nt++)
          h2a[nt] = bcast4((nt & 1) ? unp_hi(c2p[nt >> 1]) : unp_lo(c2p[nt >> 1]));
        #pragma unroll
        for (int ks = 0; ks < 2; ks++) {
          const short8 a2 = lds_frag(&hw[l15 * 36 + ks * 16 + quad * 4]);
          #pragma unroll
          for (int nt = 0; nt < 4; nt++)
            h2a[nt] = __builtin_amdgcn_mfma_f32_16x16x32_bf16(a2, bw2[ks][nt], h2a[nt], 0, 0, 0);
        }
        #pragma unroll
        for (int nt = 0; nt < 4; nt++)
          #pragma unroll
          for (int r = 0; r < 4; r++)
            hw16[(quad * 4 + r) * 72 + nt * 16 + l15] = f2b_rn(fast_tanh(h2a[nt][r]));

        f32x4 fa[2];
        #pragma unroll
        for (int dt2 = 0; dt2 < 2; dt2++)
          fa[dt2] = bcast4(dt2 ? unp_hi(c3p) : unp_lo(c3p));
        #pragma unroll
        for (int ks = 0; ks < 2; ks++) {
          const short8 a3 = lds_frag(&hw[l15 * 36 + ks * 16 + quad * 4]);
          #pragma unroll
          for (int dt2 = 0; dt2 < 2; dt2++)
            fa[dt2] = __builtin_amdgcn_mfma_f32_16x16x32_bf16(a3, bw3[ks][dt2], fa[dt2], 0, 0, 0);
        }
        #pragma unroll
        for (int dt2 = 0; dt2 < 2; dt2++)
          #pragma unroll
          for (int r = 0; r < 4; r++)
            fw16[(mt * 16 + quad * 4 + r) * 264 + e * 32 + dt2 * 16 + l15] = f2b_rn(fa[dt2][r]);
      } // mt
      __syncthreads();   // fs complete

      // ========== G1: U = tanh(x@Gw1x + (Σ_e f_e)@(Gw1dx/8) + Gb1), 2 N-tiles/wave ==========
      // Byte-identical to R12.
      {
        f32x4 u0 = bcast4(gb1a), u1 = bcast4(gb1b);
        const int mg = g1mt * 16 + l15;
        const short8 ax = lds_frag(&xdb[mg * 20 + quad * 4]);
        u0 = __builtin_amdgcn_mfma_f32_16x16x32_bf16(ax, bg1x[0], u0, 0, 0, 0);
        u1 = __builtin_amdgcn_mfma_f32_16x16x32_bf16(ax, bg1x[1], u1, 0, 0, 0);
        #pragma unroll
        for (int kb = 0; kb < 8; kb++) {
          const short8 af = lds_frag(&fsb[mg * 132 + kb * 16 + quad * 4]);
          u0 = __builtin_amdgcn_mfma_f32_16x16x32_bf16(af, bg1f[0], u0, 0, 0, 0);
          u1 = __builtin_amdgcn_mfma_f32_16x16x32_bf16(af, bg1f[1], u1, 0, 0, 0);
        }
        #pragma unroll
        for (int r = 0; r < 4; r++) {
          us16[(g1mt * 16 + quad * 4 + r) * 72 + g1n0 * 16 + l15]       = f2b_rn(fast_tanh(u0[r]));
          us16[(g1mt * 16 + quad * 4 + r) * 72 + (g1n0 + 1) * 16 + l15] = f2b_rn(fast_tanh(u1[r]));
        }
      }
      __syncthreads();   // U complete

      // ========== G2+C (wave-local): logits -> softmax -> weighted sum -> RK4 ==========
      {
        // logits for own 8 elems: A rows = elems 8e..8e+7 duplicated x2
        f32x4 lv = bcast4(gb2v);
        #pragma unroll
        for (int ks = 0; ks < 2; ks++) {
          const short8 ag = lds_frag(&usb[(e * 8 + (l15 & 7)) * 36 + ks * 16 + quad * 4]);
          lv = __builtin_amdgcn_mfma_f32_16x16x32_bf16(ag, bg2[ks], lv, 0, 0, 0);
        }
        // softmax across 8 expert lanes (l15 0..7), row r = elem (quad*4+r)&7
        float wgt[4];
        #pragma unroll
        for (int r = 0; r < 4; r++) {
          const float p = __expf(lv[r]);           // logits bounded; no max-sub (validated)
          float ssum = p + __shfl_xor(p, 1);
          ssum += __shfl_xor(ssum, 2);
          ssum += __shfl_xor(ssum, 4);
          wgt[r] = p * __builtin_amdgcn_rcpf(ssum);
        }
        // exchange weights through per-wave scratch region 1 (in-wave DS order)
        float* const wscr = (float*)(hsw + 576);   // [8 elem][8 expert] f32
        if (quad < 2 && l15 < 8) {
          #pragma unroll
          for (int r = 0; r < 4; r++)
            wscr[((quad * 4 + r) & 7) * 8 + l15] = wgt[r];
        }
        const f32x4 w0 = *(const f32x4*)&wscr[el * 8];
        const f32x4 w1 = *(const f32x4*)&wscr[el * 8 + 4];

        // weighted sum over experts for dims 4*q8..4*q8+3 of elem gr
        float kc[4] = {0.f, 0.f, 0.f, 0.f};
        #pragma unroll
        for (int j = 0; j < EE; j++) {
          const float wg = (j < 4) ? w0[j] : w1[j - 4];
          const u32x2 pf = *(const u32x2*)&fsb[gr * 132 + j * 16 + q8 * 2];
          kc[0] = __builtin_fmaf(wg, unp_lo(pf.x), kc[0]);
          kc[1] = __builtin_fmaf(wg, unp_hi(pf.x), kc[1]);
          kc[2] = __builtin_fmaf(wg, unp_lo(pf.y), kc[2]);
          kc[3] = __builtin_fmaf(wg, unp_hi(pf.y), kc[3]);
        }

        const float wk = (s == 1 || s == 2) ? 2.f : 1.f;
        const float ak = dt * (1.f / 6.f) * wk;
        #pragma unroll
        for (int q = 0; q < 4; q++) xacc[q] = __builtin_fmaf(ak, kc[q], xacc[q]);

        float xn[4];
        if (s < 3) {
          const float cn = (s == 2) ? dt : 0.5f * dt;
          #pragma unroll
          for (int q = 0; q < 4; q++) xn[q] = __builtin_fmaf(cn, kc[q], xst[q]);
        } else {
          #pragma unroll
          for (int q = 0; q < 4; q++) { xst[q] = xacc[q]; xn[q] = xacc[q]; }
          float4 o; o.x = xn[0]; o.y = xn[1]; o.z = xn[2]; o.w = xn[3];
          *(float4*)(out + (gb * TT + step + 1) * DD + 4 * q8) = o;
        }
        u32x2 p; p.x = pack2_rn(xn[0], xn[1]); p.y = pack2_rn(xn[2], xn[3]);
        *(u32x2*)&xdb[gr * 20 + q8 * 2] = p;
      }
      __syncthreads();   // xdb complete; fsb/usb free for next stage
    } // stages
  } // steps
}

extern "C" void kernel_launch(void* const* d_in, const int* in_sizes, int n_in,
                              void* d_out, int out_size, void* d_ws, size_t ws_size,
                              hipStream_t stream)
{
  const float* x0    = (const float*)d_in[0];
  const float* tspan = (const float*)d_in[1];
  const float* W1  = (const float*)d_in[2];
  const float* b1  = (const float*)d_in[3];
  const float* W2  = (const float*)d_in[4];
  const float* b2  = (const float*)d_in[5];
  const float* W3  = (const float*)d_in[6];
  const float* b3  = (const float*)d_in[7];
  const float* Gw1 = (const float*)d_in[8];
  const float* Gb1 = (const float*)d_in[9];
  const float* Gw2 = (const float*)d_in[10];
  const float* Gb2 = (const float*)d_in[11];

  // Opt in to >64 KB dynamic LDS (160 KB/CU on gfx950). Host-side, idempotent,
  // graph-capture safe. Called unconditionally every launch.
  (void)hipFuncSetAttribute((const void*)ame_ode_kernel,
                            hipFuncAttributeMaxDynamicSharedMemorySize, DYN_LDS);

  ame_ode_kernel<<<BATCH / EPB, 512, DYN_LDS, stream>>>(
      x0, tspan, W1, b1, W2, b2, W3, b3, Gw1, Gb1, Gw2, Gb2, (float*)d_out);
}

// Round 8
// 317.853 us; speedup vs baseline: 1.1068x; 1.0444x over previous
//
#include <hip/hip_runtime.h>
#include <hip/hip_bf16.h>

typedef unsigned int u32;
typedef unsigned short u16;
typedef __attribute__((ext_vector_type(8))) short short8;   // 8 bf16 (4 VGPRs) MFMA A/B frag
typedef __attribute__((ext_vector_type(4))) float f32x4;    // MFMA C/D frag
typedef __attribute__((ext_vector_type(4))) u32 u32x4;
typedef __attribute__((ext_vector_type(2))) u32 u32x2;

#define DD 32
#define EE 8
#define HH 64
#define TT 10
#define BATCH 16384
#define EPB 64          // batch elements per block (grid 256 = 1 block/CU)
#define DYN_LDS 88064   // bytes: xdb 5120 + fsb 33792 + lg 3072 + usb 9216 + scratch 36864

#if __has_builtin(__builtin_amdgcn_exp2f)
#define EXP2F(x) __builtin_amdgcn_exp2f(x)
#else
#define EXP2F(x) __builtin_exp2f(x)
#endif

__device__ __forceinline__ float fast_tanh(float x) {
  float e = EXP2F(x * 2.885390082f);
  return 1.f - 2.f * __builtin_amdgcn_rcpf(e + 1.f);
}
__device__ __forceinline__ u16 f2b_rn(float v) {
  return (u16)((__float_as_uint(v) + 0x8000u) >> 16);
}
__device__ __forceinline__ u32 pack2_rn(float a, float b) {
  return __builtin_amdgcn_perm(__float_as_uint(b) + 0x8000u,
                               __float_as_uint(a) + 0x8000u, 0x07060302u);
}
__device__ __forceinline__ float unp_lo(u32 p) { return __uint_as_float(p << 16); }
__device__ __forceinline__ float unp_hi(u32 p) { return __uint_as_float(p & 0xffff0000u); }
__device__ __forceinline__ short8 lds_frag(const u32* p) {
  u32x4 v = *(const u32x4*)p;               // ds_read_b128 (16B-aligned by construction)
  return __builtin_bit_cast(short8, v);
}
__device__ __forceinline__ f32x4 bcast4(float v) { f32x4 c; c[0]=v; c[1]=v; c[2]=v; c[3]=v; return c; }

// wave = expert (8 waves, 512 thr), 64 elems/block, grid 256 = 1 block/CU.
// == R12 structure (best: 275 us steady / 319 harness), RESTORED VERBATIM.
// Session evidence (R13-R20): every escape direction is blocked by a measured
// wall — (1) 128-VGPR allocator pin: any structure needing >128 (wave-local
// gating R15/R16/R20) spills MBs to scratch; __launch_bounds__(512,2) does NOT
// lift it. (2) DS-conflict landscape: R12's stride-132 fsb rows + u16 scatter
// h-transpose is the measured minimum (1.15e7); fsb XOR-swizzle (R13) -> 2.9e7,
// ds_read_b64_tr_b16 (R18) -> 4.2e7 (tr reads 4-way by construction, m217),
// transposed-compute b64 writes (R19) -> 2.4e7 (even-banks-only). (3) 2-block
// co-residency (R14) never materializes and halves per-wave ILP. (4) Merging
// G2+C wave-locally (R20) lengthens the per-wave serial chain (-5% both pipes).
// Kernel is co-limited: VALU ~63%, DS ~64%, MFMA ~16%, 4 barriers/stage at
// 2 waves/SIMD. Ping-pong per-wave h-scratch (mt parity) overlaps consecutive
// M-tiles; no-max-sub softmax (logits bounded, validated bit-identical R8/R13).
// REGISTER LAW (R5-R20): weights-resident needs VGPR in [100,128] -> plain
// __launch_bounds__(512) only.
__global__ __launch_bounds__(512) void ame_ode_kernel(
    const float* __restrict__ x0, const float* __restrict__ tspan,
    const float* __restrict__ W1, const float* __restrict__ b1,
    const float* __restrict__ W2, const float* __restrict__ b2,
    const float* __restrict__ W3, const float* __restrict__ b3,
    const float* __restrict__ Gw1, const float* __restrict__ Gb1,
    const float* __restrict__ Gw2, const float* __restrict__ Gb2,
    float* __restrict__ out)
{
  extern __shared__ __align__(16) u32 dynbuf[];
  u32*  const xdb = dynbuf;                    // [EPB][20] u32: xs bf16x2 (5120 B)
  u32*  const fsb = dynbuf + 1280;             // [EPB][132] u32: f bf16x2, 16B-aligned rows (33792 B)
  float* const lg = (float*)(dynbuf + 9728);   // [EPB][12]: logits (3072 B)
  u32*  const usb = dynbuf + 10496;            // [EPB][36] u32: gating U (9216 B)
  u32*  const hs  = dynbuf + 12800;            // [8 waves][2 regions][16][36] u32 scratch (36864 B)

  const int tid  = threadIdx.x;
  const int lane = tid & 63;
  const int l15  = lane & 15;
  const int quad = lane >> 4;
  const int e    = __builtin_amdgcn_readfirstlane(tid >> 6);   // wave-uniform expert id
  const int b    = blockIdx.x * EPB + lane;                    // this lane's batch element

  const float* W1f = W1 + e * (DD + 1) * HH;
  const float* b1f = b1 + e * HH;
  const float* W2f = W2 + e * HH * HH;
  const float* b2f = b2 + e * HH;
  const float* W3f = W3 + e * HH * DD;
  const float* b3f = b3 + e * DD;

  // ---- expert-weight B-frags: B[k=quad*8+j][n=l15(+16nt)] ----
  short8 bw1[4], bw2[2][4], bw3[2][2];
  #pragma unroll
  for (int nt = 0; nt < 4; nt++)
    #pragma unroll
    for (int j = 0; j < 8; j++)
      bw1[nt][j] = (short)f2b_rn(W1f[(quad * 8 + j) * HH + nt * 16 + l15]);
  #pragma unroll
  for (int ks = 0; ks < 2; ks++)
    #pragma unroll
    for (int nt = 0; nt < 4; nt++)
      #pragma unroll
      for (int j = 0; j < 8; j++)
        bw2[ks][nt][j] = (short)f2b_rn(W2f[(ks * 32 + quad * 8 + j) * HH + nt * 16 + l15]);
  #pragma unroll
  for (int ks = 0; ks < 2; ks++)
    #pragma unroll
    for (int dt2 = 0; dt2 < 2; dt2++)
      #pragma unroll
      for (int j = 0; j < 8; j++)
        bw3[ks][dt2][j] = (short)f2b_rn(W3f[(ks * 32 + quad * 8 + j) * DD + dt2 * 16 + l15]);

  // ---- G1: wave e -> M-tile e&3, N-tiles {(e>>2)*2, (e>>2)*2+1}; dx-mean folded ----
  const int g1mt = e & 3;
  const int g1n0 = (e >> 2) * 2;
  short8 bg1x[2], bg1f[2];
  #pragma unroll
  for (int ni = 0; ni < 2; ni++)
    #pragma unroll
    for (int j = 0; j < 8; j++) {
      bg1x[ni][j] = (short)f2b_rn(Gw1[(quad * 8 + j) * HH + (g1n0 + ni) * 16 + l15]);
      bg1f[ni][j] = (short)f2b_rn(0.125f * Gw1[(DD + quad * 8 + j) * HH + (g1n0 + ni) * 16 + l15]);
    }
  const float gb1a = Gb1[g1n0 * 16 + l15];
  const float gb1b = Gb1[(g1n0 + 1) * 16 + l15];

  short8 bg2[2];
  float gb2v = 0.f;
  if (e < 4) {                         // G2: waves 0-3, M-tile = e
    #pragma unroll
    for (int ks = 0; ks < 2; ks++)
      #pragma unroll
      for (int j = 0; j < 8; j++)
        bg2[ks][j] = (short)((l15 < 8) ? f2b_rn(Gw2[(ks * 32 + quad * 8 + j) * EE + l15]) : 0);
    gb2v = (l15 < 8) ? Gb2[l15] : 0.f;
  }

  // per-lane C-init components (col-only), bf16-packed
  u32 c1p[4], c2p[2], c3p;
  #pragma unroll
  for (int nt = 0; nt < 4; nt++)
    c1p[nt] = pack2_rn(b1f[nt * 16 + l15], W1f[DD * HH + nt * 16 + l15]);
  #pragma unroll
  for (int p = 0; p < 2; p++)
    c2p[p] = pack2_rn(b2f[(2 * p) * 16 + l15], b2f[(2 * p + 1) * 16 + l15]);
  c3p = pack2_rn(b3f[l15], b3f[16 + l15]);

  // ---- state init: lane owns dims 4e..4e+3 of elem = lane ----
  float xst[4], xacc[4];
  {
    const float4 v = *(const float4*)(x0 + b * DD + 4 * e);
    xst[0] = v.x; xst[1] = v.y; xst[2] = v.z; xst[3] = v.w;
    xacc[0] = v.x; xacc[1] = v.y; xacc[2] = v.z; xacc[3] = v.w;
    u32x2 p; p.x = pack2_rn(v.x, v.y); p.y = pack2_rn(v.z, v.w);
    *(u32x2*)&xdb[lane * 20 + 2 * e] = p;
    *(float4*)(out + b * TT * DD + 4 * e) = v;
  }
  __syncthreads();

  u16* const fw16 = (u16*)fsb;               // f, row stride 264 u16
  u16* const us16 = (u16*)usb;               // U, row stride 72 u16

  #pragma unroll 1
  for (int step = 0; step < TT - 1; step++) {
    const float t0 = tspan[step];
    const float t1 = tspan[step + 1];
    const float dt = t1 - t0;

    #pragma unroll 1
    for (int s = 0; s < 4; s++) {
      const float tcur = (s == 0) ? t0 : ((s == 3) ? t1 : t0 + 0.5f * dt);

      f32x4 c1i[4];
      #pragma unroll
      for (int nt = 0; nt < 4; nt++)
        c1i[nt] = bcast4(__builtin_fmaf(tcur, unp_hi(c1p[nt]), unp_lo(c1p[nt])));

      // ========== Phase A: expert MLP via MFMA (4 M-tiles, ping-pong scratch) ==========
      #pragma unroll 2
      for (int mt = 0; mt < 4; mt++) {
        u32* const hw   = hs + e * 1152 + (mt & 1) * 576;   // disjoint region per mt parity
        u16* const hw16 = (u16*)hw;

        const short8 a1 = lds_frag(&xdb[(mt * 16 + l15) * 20 + quad * 4]);
        f32x4 h1a[4];
        #pragma unroll
        for (int nt = 0; nt < 4; nt++)
          h1a[nt] = __builtin_amdgcn_mfma_f32_16x16x32_bf16(a1, bw1[nt], c1i[nt], 0, 0, 0);
        #pragma unroll
        for (int nt = 0; nt < 4; nt++)
          #pragma unroll
          for (int r = 0; r < 4; r++)
            hw16[(quad * 4 + r) * 72 + nt * 16 + l15] = f2b_rn(fast_tanh(h1a[nt][r]));

        f32x4 h2a[4];
        #pragma unroll
        for (int nt = 0; nt < 4; nt++)
          h2a[nt] = bcast4((nt & 1) ? unp_hi(c2p[nt >> 1]) : unp_lo(c2p[nt >> 1]));
        #pragma unroll
        for (int ks = 0; ks < 2; ks++) {
          const short8 a2 = lds_frag(&hw[l15 * 36 + ks * 16 + quad * 4]);
          #pragma unroll
          for (int nt = 0; nt < 4; nt++)
            h2a[nt] = __builtin_amdgcn_mfma_f32_16x16x32_bf16(a2, bw2[ks][nt], h2a[nt], 0, 0, 0);
        }
        #pragma unroll
        for (int nt = 0; nt < 4; nt++)
          #pragma unroll
          for (int r = 0; r < 4; r++)
            hw16[(quad * 4 + r) * 72 + nt * 16 + l15] = f2b_rn(fast_tanh(h2a[nt][r]));

        f32x4 fa[2];
        #pragma unroll
        for (int dt2 = 0; dt2 < 2; dt2++)
          fa[dt2] = bcast4(dt2 ? unp_hi(c3p) : unp_lo(c3p));
        #pragma unroll
        for (int ks = 0; ks < 2; ks++) {
          const short8 a3 = lds_frag(&hw[l15 * 36 + ks * 16 + quad * 4]);
          #pragma unroll
          for (int dt2 = 0; dt2 < 2; dt2++)
            fa[dt2] = __builtin_amdgcn_mfma_f32_16x16x32_bf16(a3, bw3[ks][dt2], fa[dt2], 0, 0, 0);
        }
        #pragma unroll
        for (int dt2 = 0; dt2 < 2; dt2++)
          #pragma unroll
          for (int r = 0; r < 4; r++)
            fw16[(mt * 16 + quad * 4 + r) * 264 + e * 32 + dt2 * 16 + l15] = f2b_rn(fa[dt2][r]);
      } // mt
      __syncthreads();   // fs complete

      // ========== G1: U = tanh(x@Gw1x + (Σ_e f_e)@(Gw1dx/8) + Gb1), 2 N-tiles/wave ==========
      {
        f32x4 u0 = bcast4(gb1a), u1 = bcast4(gb1b);
        const int mg = g1mt * 16 + l15;
        const short8 ax = lds_frag(&xdb[mg * 20 + quad * 4]);
        u0 = __builtin_amdgcn_mfma_f32_16x16x32_bf16(ax, bg1x[0], u0, 0, 0, 0);
        u1 = __builtin_amdgcn_mfma_f32_16x16x32_bf16(ax, bg1x[1], u1, 0, 0, 0);
        #pragma unroll
        for (int kb = 0; kb < 8; kb++) {
          const short8 af = lds_frag(&fsb[mg * 132 + kb * 16 + quad * 4]);
          u0 = __builtin_amdgcn_mfma_f32_16x16x32_bf16(af, bg1f[0], u0, 0, 0, 0);
          u1 = __builtin_amdgcn_mfma_f32_16x16x32_bf16(af, bg1f[1], u1, 0, 0, 0);
        }
        #pragma unroll
        for (int r = 0; r < 4; r++) {
          us16[(g1mt * 16 + quad * 4 + r) * 72 + g1n0 * 16 + l15]       = f2b_rn(fast_tanh(u0[r]));
          us16[(g1mt * 16 + quad * 4 + r) * 72 + (g1n0 + 1) * 16 + l15] = f2b_rn(fast_tanh(u1[r]));
        }
      }
      __syncthreads();   // U complete

      // ========== G2: logits = U @ Gw2 + Gb2 (waves 0-3, M-tile = e) ==========
      if (e < 4) {
        f32x4 lv = bcast4(gb2v);
        #pragma unroll
        for (int ks = 0; ks < 2; ks++) {
          const short8 ag = lds_frag(&usb[(e * 16 + l15) * 36 + ks * 16 + quad * 4]);
          lv = __builtin_amdgcn_mfma_f32_16x16x32_bf16(ag, bg2[ks], lv, 0, 0, 0);
        }
        if (l15 < 8) {
          #pragma unroll
          for (int r = 0; r < 4; r++)
            lg[(e * 16 + quad * 4 + r) * 12 + l15] = lv[r];
        }
      }
      __syncthreads();   // logits complete

      // ========== C: softmax (no max-sub; logits bounded) + weighted sum + RK4 ==========
      {
        const float4 la0 = *(const float4*)&lg[lane * 12 + 0];
        const float4 la1 = *(const float4*)&lg[lane * 12 + 4];
        float w8[EE];
        w8[0] = __expf(la0.x); w8[1] = __expf(la0.y);
        w8[2] = __expf(la0.z); w8[3] = __expf(la0.w);
        w8[4] = __expf(la1.x); w8[5] = __expf(la1.y);
        w8[6] = __expf(la1.z); w8[7] = __expf(la1.w);
        float ss = 0.f;
        #pragma unroll
        for (int j = 0; j < EE; j++) ss += w8[j];
        const float inv = __builtin_amdgcn_rcpf(ss);

        float kc[4] = {0.f, 0.f, 0.f, 0.f};
        #pragma unroll
        for (int j = 0; j < EE; j++) {
          const float wg = w8[j] * inv;
          const u32x2 p = *(const u32x2*)&fsb[lane * 132 + j * 16 + 2 * e];
          kc[0] = __builtin_fmaf(wg, unp_lo(p.x), kc[0]);
          kc[1] = __builtin_fmaf(wg, unp_hi(p.x), kc[1]);
          kc[2] = __builtin_fmaf(wg, unp_lo(p.y), kc[2]);
          kc[3] = __builtin_fmaf(wg, unp_hi(p.y), kc[3]);
        }

        const float wk = (s == 1 || s == 2) ? 2.f : 1.f;
        const float ak = dt * (1.f / 6.f) * wk;
        #pragma unroll
        for (int q = 0; q < 4; q++) xacc[q] = __builtin_fmaf(ak, kc[q], xacc[q]);

        float xn[4];
        if (s < 3) {
          const float cn = (s == 2) ? dt : 0.5f * dt;
          #pragma unroll
          for (int q = 0; q < 4; q++) xn[q] = __builtin_fmaf(cn, kc[q], xst[q]);
        } else {
          #pragma unroll
          for (int q = 0; q < 4; q++) { xst[q] = xacc[q]; xn[q] = xacc[q]; }
          float4 o; o.x = xn[0]; o.y = xn[1]; o.z = xn[2]; o.w = xn[3];
          *(float4*)(out + (b * TT + step + 1) * DD + 4 * e) = o;
        }
        u32x2 p; p.x = pack2_rn(xn[0], xn[1]); p.y = pack2_rn(xn[2], xn[3]);
        *(u32x2*)&xdb[lane * 20 + 2 * e] = p;
      }
      __syncthreads();   // end of stage
    } // stages
  } // steps
}

extern "C" void kernel_launch(void* const* d_in, const int* in_sizes, int n_in,
                              void* d_out, int out_size, void* d_ws, size_t ws_size,
                              hipStream_t stream)
{
  const float* x0    = (const float*)d_in[0];
  const float* tspan = (const float*)d_in[1];
  const float* W1  = (const float*)d_in[2];
  const float* b1  = (const float*)d_in[3];
  const float* W2  = (const float*)d_in[4];
  const float* b2  = (const float*)d_in[5];
  const float* W3  = (const float*)d_in[6];
  const float* b3  = (const float*)d_in[7];
  const float* Gw1 = (const float*)d_in[8];
  const float* Gb1 = (const float*)d_in[9];
  const float* Gw2 = (const float*)d_in[10];
  const float* Gb2 = (const float*)d_in[11];

  // Opt in to >64 KB dynamic LDS (160 KB/CU on gfx950). Host-side, idempotent,
  // graph-capture safe. Called unconditionally every launch.
  (void)hipFuncSetAttribute((const void*)ame_ode_kernel,
                            hipFuncAttributeMaxDynamicSharedMemorySize, DYN_LDS);

  ame_ode_kernel<<<BATCH / EPB, 512, DYN_LDS, stream>>>(
      x0, tspan, W1, b1, W2, b2, W3, b3, Gw1, Gb1, Gw2, Gb2, (float*)d_out);
}